// Round 4
// baseline (249.623 us; speedup 1.0000x reference)
//
#include <hip/hip_runtime.h>
#include <hip/hip_bf16.h>

#define N_NODES 20000
#define MPAD    20096   // 157 * 128
#define E_EDGES 400000
#define LATENT 128
#define H1 256
#define HIDDEN 512
#define OUT_D 64
#define HEADS 4
#define NEG_SLOPE 0.2f
#define NBLK_SCAN ((N_NODES + 255) / 256)   // 79

typedef __attribute__((ext_vector_type(8))) __bf16 bf16x8;
typedef __attribute__((ext_vector_type(4))) float f32x4;
typedef __attribute__((ext_vector_type(4))) unsigned short u16x4;

__device__ __forceinline__ unsigned short f2bf(float f) {
    union { float f; unsigned int u; } v; v.f = f;
    unsigned int r = v.u + 0x7fffu + ((v.u >> 16) & 1u);  // RNE
    return (unsigned short)(r >> 16);
}
__device__ __forceinline__ float bf2f(unsigned short u) {
    union { unsigned int u; float f; } v; v.u = ((unsigned int)u) << 16;
    return v.f;
}

// async global->LDS, 16 B per lane; LDS dest must be wave-uniform base (+lane*16 implicit)
__device__ __forceinline__ void gl_lds16(const unsigned short* g, unsigned short* l) {
    __builtin_amdgcn_global_load_lds(
        (const __attribute__((address_space(1))) unsigned int*)g,
        (__attribute__((address_space(3))) unsigned int*)l,
        16, 0, 0);
}

// ---------------- fp32 -> bf16 convert + pad rows (for z) ----------------
__global__ void convert_pad_z(const float* __restrict__ z, unsigned short* __restrict__ zb) {
    int t = blockIdx.x * blockDim.x + threadIdx.x;
    if (t >= MPAD * LATENT) return;
    int row = t >> 7;  // LATENT = 128
    zb[t] = f2bf(row < N_NODES ? z[t] : 0.f);
}

// ---------------- fp32 [K][N] -> bf16 [N][K] transpose-convert (weights) ----------------
__global__ void convert_transpose(const float* __restrict__ W, unsigned short* __restrict__ Wt,
                                  int K, int N) {
    int t = blockIdx.x * blockDim.x + threadIdx.x;
    if (t >= K * N) return;
    int k = t / N, n = t - k * N;
    Wt[n * K + k] = f2bf(W[t]);
}

// ---------------- bf16 MFMA GEMM (m97 structure): C = act(A @ Bt^T + bias) ----------------
// 128x128 tile, BK=64, global_load_lds width-16 staging, operand-swapped MFMA so the
// accumulator regs run along N -> packed 8B epilogue stores.
template<int OUT_BF16>
__global__ __launch_bounds__(256)
void gemm_mfma_bt(const unsigned short* __restrict__ A,
                  const unsigned short* __restrict__ Bt,
                  const float* __restrict__ bias,
                  void* __restrict__ Cv,
                  int K, int N, int do_relu) {
    __shared__ unsigned short As[128 * 64];
    __shared__ unsigned short Bs[128 * 64];
    const int tid = threadIdx.x;
    const int wave = tid >> 6, lane = tid & 63;
    const int m0 = blockIdx.y * 128, n0 = blockIdx.x * 128;
    const int wm = (wave >> 1) * 64, wn = (wave & 1) * 64;
    const int fr = lane & 15, q = lane >> 4;
    const int lr = lane >> 3, lc = lane & 7;   // staging: row-within-8 / 16B chunk

    f32x4 acc[4][4] = {};

    for (int k0 = 0; k0 < K; k0 += 64) {
        __syncthreads();
#pragma unroll
        for (int j = 0; j < 4; j++) {
            const int rbase = wave * 32 + j * 8;   // 8 rows (1 KB) per instruction
            gl_lds16(A  + (size_t)(m0 + rbase + lr) * K + k0 + lc * 8, As + rbase * 64);
            gl_lds16(Bt + (size_t)(n0 + rbase + lr) * K + k0 + lc * 8, Bs + rbase * 64);
        }
        __syncthreads();   // drains vmcnt (global_load_lds) for all waves
#pragma unroll
        for (int kt = 0; kt < 2; kt++) {
            bf16x8 af[4], bfr[4];
#pragma unroll
            for (int t = 0; t < 4; t++) {
                af[t]  = *(const bf16x8*)(As + (wm + t * 16 + fr) * 64 + kt * 32 + q * 8);
                bfr[t] = *(const bf16x8*)(Bs + (wn + t * 16 + fr) * 64 + kt * 32 + q * 8);
            }
#pragma unroll
            for (int mt = 0; mt < 4; mt++)
#pragma unroll
                for (int nt = 0; nt < 4; nt++)
                    // swapped operands: D[row=q*4+r -> N, col=fr -> M] => regs run along N
                    acc[mt][nt] = __builtin_amdgcn_mfma_f32_16x16x32_bf16(
                        bfr[nt], af[mt], acc[mt][nt], 0, 0, 0);
        }
    }

    // epilogue: lane holds C[m0+wm+mt*16+fr][n0+wn+nt*16+q*4 .. +3]
#pragma unroll
    for (int mt = 0; mt < 4; mt++) {
        const int row = m0 + wm + mt * 16 + fr;
#pragma unroll
        for (int nt = 0; nt < 4; nt++) {
            const int colb = n0 + wn + nt * 16 + q * 4;
            f32x4 bv = {0.f, 0.f, 0.f, 0.f};
            if (bias) bv = *(const f32x4*)(bias + colb);
            f32x4 v;
#pragma unroll
            for (int r = 0; r < 4; r++) {
                float x = acc[mt][nt][r] + bv[r];
                if (do_relu) x = fmaxf(x, 0.f);
                v[r] = x;
            }
            if (OUT_BF16) {
                u16x4 p = { f2bf(v[0]), f2bf(v[1]), f2bf(v[2]), f2bf(v[3]) };
                *(u16x4*)((unsigned short*)Cv + (size_t)row * N + colb) = p;
            } else {
                *(f32x4*)((float*)Cv + (size_t)row * N + colb) = v;
            }
        }
    }
}

// ---------------- attention coefficients from bf16 h ----------------
__global__ void att_coef_kernel(const unsigned short* __restrict__ hb,
                                const float* __restrict__ att_src,
                                const float* __restrict__ att_dst,
                                float* __restrict__ a_src, float* __restrict__ a_dst) {
    int wave = blockIdx.x * (blockDim.x >> 6) + (threadIdx.x >> 6);
    int lane = threadIdx.x & 63;
    if (wave >= N_NODES * HEADS) return;
    int head = wave & (HEADS - 1);
    float hv = bf2f(hb[wave * OUT_D + lane]);
    float vs = hv * att_src[head * OUT_D + lane];
    float vd = hv * att_dst[head * OUT_D + lane];
#pragma unroll
    for (int off = 32; off > 0; off >>= 1) {
        vs += __shfl_down(vs, off, 64);
        vd += __shfl_down(vd, off, 64);
    }
    if (lane == 0) {
        a_src[wave] = vs;
        a_dst[wave] = vd;
    }
}

// ---------------- CSR build ----------------
__global__ void hist_kernel(const int* __restrict__ ei, int* __restrict__ deg) {
    int t = blockIdx.x * blockDim.x + threadIdx.x;
    if (t < E_EDGES) atomicAdd(&deg[ei[E_EDGES + t]], 1);
}

__global__ __launch_bounds__(256) void scan_a(const int* __restrict__ deg,
                                              int* __restrict__ t, int* __restrict__ bsum) {
    int i = blockIdx.x * 256 + threadIdx.x;
    int lane = threadIdx.x & 63, wave = threadIdx.x >> 6;
    int v = (i < N_NODES) ? deg[i] + 1 : 0;
    int s = v;
#pragma unroll
    for (int off = 1; off < 64; off <<= 1) {
        int u = __shfl_up(s, off, 64);
        if (lane >= off) s += u;
    }
    __shared__ int wsum[4];
    if (lane == 63) wsum[wave] = s;
    __syncthreads();
    int woff = 0;
    for (int w = 0; w < wave; w++) woff += wsum[w];
    s += woff;
    if (i < N_NODES) t[i] = s;
    if (threadIdx.x == 255) bsum[blockIdx.x] = s;
}

__global__ void scan_b(const int* __restrict__ bsum, int* __restrict__ boff) {
    int lane = threadIdx.x;  // 64 threads
    int carry = 0;
    for (int c = 0; c < (NBLK_SCAN + 63) / 64; c++) {
        int idx = c * 64 + lane;
        int v = (idx < NBLK_SCAN) ? bsum[idx] : 0;
        int s = v;
#pragma unroll
        for (int off = 1; off < 64; off <<= 1) {
            int u = __shfl_up(s, off, 64);
            if (lane >= off) s += u;
        }
        if (idx < NBLK_SCAN) boff[idx] = carry + s - v;
        carry += __shfl(s, 63, 64);
    }
}

__global__ __launch_bounds__(256) void scan_c(const int* __restrict__ t, const int* __restrict__ deg,
                                              const int* __restrict__ boff,
                                              int* __restrict__ row_start, int* __restrict__ cursor,
                                              int* __restrict__ adj) {
    int i = blockIdx.x * 256 + threadIdx.x;
    if (i >= N_NODES) return;
    int incl = t[i] + boff[blockIdx.x];
    int start = incl - (deg[i] + 1);
    row_start[i] = start;
    cursor[i] = start;
    adj[start + deg[i]] = i;  // self-loop in last slot
}

__global__ void scatter_kernel(const int* __restrict__ ei, int* __restrict__ cursor,
                               int* __restrict__ adj) {
    int t = blockIdx.x * blockDim.x + threadIdx.x;
    if (t >= E_EDGES) return;
    int d = ei[E_EDGES + t];
    int slot = atomicAdd(&cursor[d], 1);
    adj[slot] = ei[t];
}

// ---------------- fused segment-softmax + gather-aggregate ----------------
// block = one dst node. Phase 1: wave = head (softmax stats, normalized weights to LDS).
// Phase 2: wave w processes edges w, w+4, ...; lane l covers head l>>4, dims (l&15)*4..+3
// via one ushort4 load (512 B contiguous per edge). No atomics.
__global__ __launch_bounds__(256) void fused_gat(const int* __restrict__ adj,
                                                 const int* __restrict__ row_start,
                                                 const int* __restrict__ deg,
                                                 const float* __restrict__ a_src,
                                                 const float* __restrict__ a_dst,
                                                 const unsigned short* __restrict__ hb,
                                                 const float* __restrict__ bias_g,
                                                 float* __restrict__ out) {
    const int d = blockIdx.x;
    const int wave = threadIdx.x >> 6, lane = threadIdx.x & 63;
    const int base = row_start[d];
    const int cnt = deg[d] + 1;

    __shared__ int   sidx[64];
    __shared__ float wv[HEADS][64];
    __shared__ float smx[HEADS], sinv[HEADS];
    __shared__ float red[4][64][4];

    // ---- phase 1: wave = head ----
    {
        const int head = wave;
        const float ad = a_dst[d * HEADS + head];
        float mx = -1e30f, v0 = 0.f;
        int s0 = 0;
        const bool has = (lane < cnt);
        if (has) {
            s0 = adj[base + lane];
            float v = a_src[s0 * HEADS + head] + ad;
            v0 = (v > 0.f) ? v : NEG_SLOPE * v;
            mx = v0;
        }
        for (int e = lane + 64; e < cnt; e += 64) {   // rare (deg >= 64)
            int s = adj[base + e];
            float v = a_src[s * HEADS + head] + ad;
            v = (v > 0.f) ? v : NEG_SLOPE * v;
            mx = fmaxf(mx, v);
        }
#pragma unroll
        for (int off = 32; off > 0; off >>= 1) mx = fmaxf(mx, __shfl_xor(mx, off, 64));

        float sm = has ? __expf(v0 - mx) : 0.f;
        for (int e = lane + 64; e < cnt; e += 64) {
            int s = adj[base + e];
            float v = a_src[s * HEADS + head] + ad;
            v = (v > 0.f) ? v : NEG_SLOPE * v;
            sm += __expf(v - mx);
        }
#pragma unroll
        for (int off = 32; off > 0; off >>= 1) sm += __shfl_xor(sm, off, 64);
        const float inv = 1.f / (sm + 1e-16f);

        if (has) wv[head][lane] = __expf(v0 - mx) * inv;
        if (wave == 0 && has) sidx[lane] = s0;
        if (lane == 0) { smx[head] = mx; sinv[head] = inv; }
    }
    __syncthreads();

    // ---- phase 2: wave-strided edges, lane covers (head, 4 dims) ----
    const int head = lane >> 4;
    float a0 = 0.f, a1 = 0.f, a2 = 0.f, a3 = 0.f;
    for (int e = wave; e < cnt; e += 4) {
        int s; float w;
        if (e < 64) {
            s = sidx[e];
            w = wv[head][e];
        } else {  // rare fallback
            s = adj[base + e];
            float v = a_src[s * HEADS + head] + a_dst[d * HEADS + head];
            v = (v > 0.f) ? v : NEG_SLOPE * v;
            w = __expf(v - smx[head]) * sinv[head];
        }
        u16x4 hx = *(const u16x4*)(hb + (size_t)s * (HEADS * OUT_D) + lane * 4);
        a0 += w * bf2f(hx[0]);
        a1 += w * bf2f(hx[1]);
        a2 += w * bf2f(hx[2]);
        a3 += w * bf2f(hx[3]);
    }
    red[wave][lane][0] = a0; red[wave][lane][1] = a1;
    red[wave][lane][2] = a2; red[wave][lane][3] = a3;
    __syncthreads();

    // ---- combine: mean over heads + bias ----
    if (wave == 0) {
        const int a = lane >> 2, b = lane & 3;
        float r = 0.f;
#pragma unroll
        for (int w2 = 0; w2 < 4; w2++)
#pragma unroll
            for (int h = 0; h < 4; h++)
                r += red[w2][h * 16 + a][b];
        out[d * OUT_D + lane] = 0.25f * r + bias_g[lane];
    }
}

extern "C" void kernel_launch(void* const* d_in, const int* in_sizes, int n_in,
                              void* d_out, int out_size, void* d_ws, size_t ws_size,
                              hipStream_t stream) {
    const float* z       = (const float*)d_in[0];
    const float* W1      = (const float*)d_in[1];
    const float* b1      = (const float*)d_in[2];
    const float* W2      = (const float*)d_in[3];
    const float* b2      = (const float*)d_in[4];
    const float* Wg      = (const float*)d_in[5];
    const float* att_src = (const float*)d_in[6];
    const float* att_dst = (const float*)d_in[7];
    const float* bias_g  = (const float*)d_in[8];
    const int*   ei      = (const int*)d_in[9];
    float* out = (float*)d_out;

    char* ws = (char*)d_ws;
    size_t off = 0;
    auto carve = [&](size_t bytes) { void* p = ws + off; off += (bytes + 255) & ~(size_t)255; return p; };

    unsigned short* zb  = (unsigned short*)carve((size_t)MPAD * LATENT * 2);
    unsigned short* x1b = (unsigned short*)carve((size_t)MPAD * H1 * 2);
    unsigned short* x2b = (unsigned short*)carve((size_t)MPAD * HIDDEN * 2);
    unsigned short* W1t = (unsigned short*)carve((size_t)H1 * LATENT * 2);
    unsigned short* W2t = (unsigned short*)carve((size_t)HIDDEN * H1 * 2);
    unsigned short* Wgt = (unsigned short*)carve((size_t)(HEADS * OUT_D) * HIDDEN * 2);
    unsigned short* hb  = (unsigned short*)carve((size_t)MPAD * HEADS * OUT_D * 2);
    float* a_src = (float*)carve((size_t)N_NODES * HEADS * 4);
    float* a_dst = (float*)carve((size_t)N_NODES * HEADS * 4);
    int* deg       = (int*)carve((size_t)N_NODES * 4);
    int* tmp_scan  = (int*)carve((size_t)N_NODES * 4);
    int* bsum      = (int*)carve((size_t)NBLK_SCAN * 4);
    int* boff      = (int*)carve((size_t)NBLK_SCAN * 4);
    int* row_start = (int*)carve((size_t)N_NODES * 4);
    int* cursor    = (int*)carve((size_t)N_NODES * 4);
    int* adj       = (int*)carve((size_t)(E_EDGES + N_NODES) * 4);

    hipMemsetAsync(deg, 0, (size_t)N_NODES * 4, stream);

    // bf16 conversions
    convert_pad_z<<<(MPAD * LATENT + 255) / 256, 256, 0, stream>>>(z, zb);
    convert_transpose<<<(LATENT * H1 + 255) / 256, 256, 0, stream>>>(W1, W1t, LATENT, H1);
    convert_transpose<<<(H1 * HIDDEN + 255) / 256, 256, 0, stream>>>(W2, W2t, H1, HIDDEN);
    convert_transpose<<<(HIDDEN * HEADS * OUT_D + 255) / 256, 256, 0, stream>>>(Wg, Wgt, HIDDEN, HEADS * OUT_D);

    // CSR build
    hist_kernel<<<(E_EDGES + 255) / 256, 256, 0, stream>>>(ei, deg);
    scan_a<<<NBLK_SCAN, 256, 0, stream>>>(deg, tmp_scan, bsum);
    scan_b<<<1, 64, 0, stream>>>(bsum, boff);
    scan_c<<<NBLK_SCAN, 256, 0, stream>>>(tmp_scan, deg, boff, row_start, cursor, adj);
    scatter_kernel<<<(E_EDGES + 255) / 256, 256, 0, stream>>>(ei, cursor, adj);

    // GEMMs (MFMA, m97-style staging)
    gemm_mfma_bt<1><<<dim3(H1 / 128, MPAD / 128), 256, 0, stream>>>(zb,  W1t, b1, x1b, LATENT, H1, 1);
    gemm_mfma_bt<1><<<dim3(HIDDEN / 128, MPAD / 128), 256, 0, stream>>>(x1b, W2t, b2, x2b, H1, HIDDEN, 1);
    gemm_mfma_bt<1><<<dim3((HEADS * OUT_D) / 128, MPAD / 128), 256, 0, stream>>>(x2b, Wgt, nullptr, hb, HIDDEN, HEADS * OUT_D, 0);

    // attention coefficients
    int waves_per_block = 256 / 64;
    int n_waves = N_NODES * HEADS;
    att_coef_kernel<<<(n_waves + waves_per_block - 1) / waves_per_block, 256, 0, stream>>>(hb, att_src, att_dst, a_src, a_dst);

    // fused softmax + aggregate (no atomics)
    fused_gat<<<N_NODES, 256, 0, stream>>>(adj, row_start, deg, a_src, a_dst, hb, bias_g, out);
}

// Round 5
// 223.833 us; speedup vs baseline: 1.1152x; 1.1152x over previous
//
#include <hip/hip_runtime.h>
#include <hip/hip_bf16.h>

#define N_NODES 20000
#define MPAD    20096   // 314 * 64
#define E_EDGES 400000
#define LATENT 128
#define H1 256
#define HIDDEN 512
#define OUT_D 64
#define HEADS 4
#define NEG_SLOPE 0.2f
#define NBLK_SCAN ((N_NODES + 255) / 256)   // 79

typedef __attribute__((ext_vector_type(8))) __bf16 bf16x8;
typedef __attribute__((ext_vector_type(4))) float f32x4;
typedef __attribute__((ext_vector_type(4))) unsigned short u16x4;

__device__ __forceinline__ unsigned short f2bf(float f) {
    union { float f; unsigned int u; } v; v.f = f;
    unsigned int r = v.u + 0x7fffu + ((v.u >> 16) & 1u);  // RNE
    return (unsigned short)(r >> 16);
}
__device__ __forceinline__ float bf2f(unsigned short u) {
    union { unsigned int u; float f; } v; v.u = ((unsigned int)u) << 16;
    return v.f;
}

__device__ __forceinline__ void gl_lds16(const unsigned short* g, unsigned short* l) {
    __builtin_amdgcn_global_load_lds(
        (const __attribute__((address_space(1))) unsigned int*)g,
        (__attribute__((address_space(3))) unsigned int*)l,
        16, 0, 0);
}

// ---------------- all fp32->bf16 conversions in ONE launch ----------------
#define SEG0 (MPAD * LATENT)
#define SEG1 (LATENT * H1)
#define SEG2 (H1 * HIDDEN)
#define SEG3 (HIDDEN * HEADS * OUT_D)
__global__ void convert_all(const float* __restrict__ z, const float* __restrict__ W1,
                            const float* __restrict__ W2, const float* __restrict__ Wg,
                            unsigned short* __restrict__ zb, unsigned short* __restrict__ W1t,
                            unsigned short* __restrict__ W2t, unsigned short* __restrict__ Wgt) {
    int t = blockIdx.x * blockDim.x + threadIdx.x;
    if (t < SEG0) { int row = t >> 7; zb[t] = f2bf(row < N_NODES ? z[t] : 0.f); return; }
    t -= SEG0;
    if (t < SEG1) { int k = t >> 8, n = t & 255; W1t[n * LATENT + k] = f2bf(W1[t]); return; }
    t -= SEG1;
    if (t < SEG2) { int k = t >> 9, n = t & 511; W2t[n * H1 + k] = f2bf(W2[t]); return; }
    t -= SEG2;
    if (t < SEG3) { int k = t >> 8, n = t & 255; Wgt[n * HIDDEN + k] = f2bf(Wg[t]); }
}

// ---------------- bf16 MFMA GEMM: 64x128 tile, BK=64, global_load_lds staging ----------------
// Swapped-operand MFMA: accumulator regs run along N -> packed 8B stores.
template<int OUT_BF16>
__global__ __launch_bounds__(256)
void gemm_mfma_bt(const unsigned short* __restrict__ A,
                  const unsigned short* __restrict__ Bt,
                  const float* __restrict__ bias,
                  void* __restrict__ Cv,
                  int K, int N, int do_relu) {
    __shared__ unsigned short As[64 * 64];
    __shared__ unsigned short Bs[128 * 64];
    const int tid = threadIdx.x;
    const int wave = tid >> 6, lane = tid & 63;
    const int m0 = blockIdx.y * 64, n0 = blockIdx.x * 128;
    const int wm = (wave >> 1) * 32, wn = (wave & 1) * 64;
    const int fr = lane & 15, q = lane >> 4;
    const int lr = lane >> 3, lc = lane & 7;

    f32x4 acc[2][4] = {};

    for (int k0 = 0; k0 < K; k0 += 64) {
        __syncthreads();
#pragma unroll
        for (int j = 0; j < 2; j++) {          // A: 64 rows, 8 instrs total
            const int rbase = wave * 16 + j * 8;
            gl_lds16(A + (size_t)(m0 + rbase + lr) * K + k0 + lc * 8, As + rbase * 64);
        }
#pragma unroll
        for (int j = 0; j < 4; j++) {          // B: 128 rows, 16 instrs total
            const int rbase = wave * 32 + j * 8;
            gl_lds16(Bt + (size_t)(n0 + rbase + lr) * K + k0 + lc * 8, Bs + rbase * 64);
        }
        __syncthreads();
#pragma unroll
        for (int kt = 0; kt < 2; kt++) {
            bf16x8 af[2], bfr[4];
#pragma unroll
            for (int t = 0; t < 2; t++)
                af[t] = *(const bf16x8*)(As + (wm + t * 16 + fr) * 64 + kt * 32 + q * 8);
#pragma unroll
            for (int t = 0; t < 4; t++)
                bfr[t] = *(const bf16x8*)(Bs + (wn + t * 16 + fr) * 64 + kt * 32 + q * 8);
#pragma unroll
            for (int mt = 0; mt < 2; mt++)
#pragma unroll
                for (int nt = 0; nt < 4; nt++)
                    acc[mt][nt] = __builtin_amdgcn_mfma_f32_16x16x32_bf16(
                        bfr[nt], af[mt], acc[mt][nt], 0, 0, 0);
        }
    }

#pragma unroll
    for (int mt = 0; mt < 2; mt++) {
        const int row = m0 + wm + mt * 16 + fr;
#pragma unroll
        for (int nt = 0; nt < 4; nt++) {
            const int colb = n0 + wn + nt * 16 + q * 4;
            f32x4 bv = {0.f, 0.f, 0.f, 0.f};
            if (bias) bv = *(const f32x4*)(bias + colb);
            f32x4 v;
#pragma unroll
            for (int r = 0; r < 4; r++) {
                float x = acc[mt][nt][r] + bv[r];
                if (do_relu) x = fmaxf(x, 0.f);
                v[r] = x;
            }
            if (OUT_BF16) {
                u16x4 p = { f2bf(v[0]), f2bf(v[1]), f2bf(v[2]), f2bf(v[3]) };
                *(u16x4*)((unsigned short*)Cv + (size_t)row * N + colb) = p;
            } else {
                *(f32x4*)((float*)Cv + (size_t)row * N + colb) = v;
            }
        }
    }
}

// ---------------- attention coefficients: one wave per node, vectorized ----------------
__global__ void att_coef_kernel(const unsigned short* __restrict__ hb,
                                const float* __restrict__ att_src,
                                const float* __restrict__ att_dst,
                                float* __restrict__ a_src, float* __restrict__ a_dst) {
    int node = blockIdx.x * (blockDim.x >> 6) + (threadIdx.x >> 6);
    int lane = threadIdx.x & 63;
    if (node >= N_NODES) return;
    const int head = lane >> 4, db = (lane & 15) * 4;
    u16x4 hx = *(const u16x4*)(hb + (size_t)node * (HEADS * OUT_D) + lane * 4);
    float vs = 0.f, vd = 0.f;
#pragma unroll
    for (int j = 0; j < 4; j++) {
        float hv = bf2f(hx[j]);
        vs += hv * att_src[head * OUT_D + db + j];
        vd += hv * att_dst[head * OUT_D + db + j];
    }
#pragma unroll
    for (int off = 1; off < 16; off <<= 1) {   // reduce within 16-lane head group
        vs += __shfl_xor(vs, off, 64);
        vd += __shfl_xor(vd, off, 64);
    }
    if ((lane & 15) == 0) {
        a_src[node * HEADS + head] = vs;
        a_dst[node * HEADS + head] = vd;
    }
}

// ---------------- CSR build ----------------
__global__ void hist_kernel(const int* __restrict__ ei, int* __restrict__ deg) {
    int t = blockIdx.x * blockDim.x + threadIdx.x;
    if (t < E_EDGES) atomicAdd(&deg[ei[E_EDGES + t]], 1);
}

__global__ __launch_bounds__(256) void scan_a(const int* __restrict__ deg,
                                              int* __restrict__ t, int* __restrict__ bsum) {
    int i = blockIdx.x * 256 + threadIdx.x;
    int lane = threadIdx.x & 63, wave = threadIdx.x >> 6;
    int v = (i < N_NODES) ? deg[i] + 1 : 0;
    int s = v;
#pragma unroll
    for (int off = 1; off < 64; off <<= 1) {
        int u = __shfl_up(s, off, 64);
        if (lane >= off) s += u;
    }
    __shared__ int wsum[4];
    if (lane == 63) wsum[wave] = s;
    __syncthreads();
    int woff = 0;
    for (int w = 0; w < wave; w++) woff += wsum[w];
    s += woff;
    if (i < N_NODES) t[i] = s;
    if (threadIdx.x == 255) bsum[blockIdx.x] = s;
}

__global__ void scan_b(const int* __restrict__ bsum, int* __restrict__ boff) {
    int lane = threadIdx.x;  // 64 threads
    int carry = 0;
    for (int c = 0; c < (NBLK_SCAN + 63) / 64; c++) {
        int idx = c * 64 + lane;
        int v = (idx < NBLK_SCAN) ? bsum[idx] : 0;
        int s = v;
#pragma unroll
        for (int off = 1; off < 64; off <<= 1) {
            int u = __shfl_up(s, off, 64);
            if (lane >= off) s += u;
        }
        if (idx < NBLK_SCAN) boff[idx] = carry + s - v;
        carry += __shfl(s, 63, 64);
    }
}

__global__ __launch_bounds__(256) void scan_c(const int* __restrict__ t, const int* __restrict__ deg,
                                              const int* __restrict__ boff,
                                              int* __restrict__ row_start, int* __restrict__ cursor) {
    int i = blockIdx.x * 256 + threadIdx.x;
    if (i >= N_NODES) return;
    int incl = t[i] + boff[blockIdx.x];
    int start = incl - (deg[i] + 1);
    row_start[i] = start;
    cursor[i] = start;
}

// ---------------- scatter edges + precompute leaky-relu'd logits (all 4 heads) ----------------
// Edge-parallel: 420k independent threads hide the random-gather latency that used to sit
// on fused_gat's per-block critical path. Covers self-loop slots too (t >= E).
__global__ void scatter_logits(const int* __restrict__ ei, int* __restrict__ cursor,
                               const int* __restrict__ row_start, const int* __restrict__ deg,
                               const float* __restrict__ a_src, const float* __restrict__ a_dst,
                               int* __restrict__ adj, float* __restrict__ elog) {
    int t = blockIdx.x * blockDim.x + threadIdx.x;
    if (t >= E_EDGES + N_NODES) return;
    int s, d, slot;
    if (t < E_EDGES) {
        s = ei[t]; d = ei[E_EDGES + t];
        slot = atomicAdd(&cursor[d], 1);
    } else {
        s = d = t - E_EDGES;
        slot = row_start[d] + deg[d];
    }
    adj[slot] = s;
    f32x4 as = *(const f32x4*)(a_src + s * HEADS);
    f32x4 ad = *(const f32x4*)(a_dst + d * HEADS);
    f32x4 o;
#pragma unroll
    for (int h = 0; h < HEADS; h++) {
        float v = as[h] + ad[h];
        o[h] = (v > 0.f) ? v : NEG_SLOPE * v;
    }
    *(f32x4*)(elog + (size_t)slot * HEADS) = o;
}

// ---------------- fused segment-softmax + gather-aggregate ----------------
// block = dst node. Phase 1 (wave = head): contiguous elog reads -> max/sum -> weights in LDS.
// Phase 2: wave-strided edges, lane covers (head, 4 dims), unroll-2 for gather ILP. No atomics.
__global__ __launch_bounds__(256) void fused_gat(const int* __restrict__ adj,
                                                 const int* __restrict__ row_start,
                                                 const int* __restrict__ deg,
                                                 const float* __restrict__ elog,
                                                 const unsigned short* __restrict__ hb,
                                                 const float* __restrict__ bias_g,
                                                 float* __restrict__ out) {
    const int d = blockIdx.x;
    const int wave = threadIdx.x >> 6, lane = threadIdx.x & 63;
    const int base = row_start[d];
    const int cnt = deg[d] + 1;

    __shared__ int   sidx[64];
    __shared__ float wv[HEADS][64];
    __shared__ float smx[HEADS], sinv[HEADS];
    __shared__ float red[4][64][4];

    // ---- phase 1: wave = head; contiguous elog ----
    {
        const int head = wave;
        const bool has = (lane < cnt);
        float v0 = has ? elog[(size_t)(base + lane) * HEADS + head] : -1e30f;
        if (wave == 0 && has) sidx[lane] = adj[base + lane];
        float mx = v0;
        for (int e = lane + 64; e < cnt; e += 64)   // rare (deg >= 64)
            mx = fmaxf(mx, elog[(size_t)(base + e) * HEADS + head]);
#pragma unroll
        for (int off = 32; off > 0; off >>= 1) mx = fmaxf(mx, __shfl_xor(mx, off, 64));

        float ex0 = has ? __expf(v0 - mx) : 0.f;
        float sm = ex0;
        for (int e = lane + 64; e < cnt; e += 64)
            sm += __expf(elog[(size_t)(base + e) * HEADS + head] - mx);
#pragma unroll
        for (int off = 32; off > 0; off >>= 1) sm += __shfl_xor(sm, off, 64);
        const float inv = 1.f / (sm + 1e-16f);

        if (has) wv[head][lane] = ex0 * inv;
        if (lane == 0) { smx[head] = mx; sinv[head] = inv; }
    }
    __syncthreads();

    // ---- phase 2: wave-strided edges, unroll-2 ----
    const int head = lane >> 4;
    float a0 = 0.f, a1 = 0.f, a2 = 0.f, a3 = 0.f;
    const int lim = cnt < 64 ? cnt : 64;
    for (int e = wave; e < lim; e += 8) {
        int s1 = sidx[e];
        float w1 = wv[head][e];
        const u16x4 h1 = *(const u16x4*)(hb + (size_t)s1 * (HEADS * OUT_D) + lane * 4);
        const int e2 = e + 4;
        if (e2 < lim) {
            int s2 = sidx[e2];
            float w2 = wv[head][e2];
            const u16x4 h2 = *(const u16x4*)(hb + (size_t)s2 * (HEADS * OUT_D) + lane * 4);
            a0 += w1 * bf2f(h1[0]) + w2 * bf2f(h2[0]);
            a1 += w1 * bf2f(h1[1]) + w2 * bf2f(h2[1]);
            a2 += w1 * bf2f(h1[2]) + w2 * bf2f(h2[2]);
            a3 += w1 * bf2f(h1[3]) + w2 * bf2f(h2[3]);
        } else {
            a0 += w1 * bf2f(h1[0]);
            a1 += w1 * bf2f(h1[1]);
            a2 += w1 * bf2f(h1[2]);
            a3 += w1 * bf2f(h1[3]);
        }
    }
    for (int e = 64 + wave; e < cnt; e += 4) {   // rare fallback
        int s = adj[base + e];
        float w = __expf(elog[(size_t)(base + e) * HEADS + head] - smx[head]) * sinv[head];
        const u16x4 hx = *(const u16x4*)(hb + (size_t)s * (HEADS * OUT_D) + lane * 4);
        a0 += w * bf2f(hx[0]); a1 += w * bf2f(hx[1]);
        a2 += w * bf2f(hx[2]); a3 += w * bf2f(hx[3]);
    }
    red[wave][lane][0] = a0; red[wave][lane][1] = a1;
    red[wave][lane][2] = a2; red[wave][lane][3] = a3;
    __syncthreads();

    // ---- combine: mean over heads + bias ----
    if (wave == 0) {
        const int a = lane >> 2, b = lane & 3;
        float r = 0.f;
#pragma unroll
        for (int w2 = 0; w2 < 4; w2++)
#pragma unroll
            for (int h = 0; h < 4; h++)
                r += red[w2][h * 16 + a][b];
        out[d * OUT_D + lane] = 0.25f * r + bias_g[lane];
    }
}

extern "C" void kernel_launch(void* const* d_in, const int* in_sizes, int n_in,
                              void* d_out, int out_size, void* d_ws, size_t ws_size,
                              hipStream_t stream) {
    const float* z       = (const float*)d_in[0];
    const float* W1      = (const float*)d_in[1];
    const float* b1      = (const float*)d_in[2];
    const float* W2      = (const float*)d_in[3];
    const float* b2      = (const float*)d_in[4];
    const float* Wg      = (const float*)d_in[5];
    const float* att_src = (const float*)d_in[6];
    const float* att_dst = (const float*)d_in[7];
    const float* bias_g  = (const float*)d_in[8];
    const int*   ei      = (const int*)d_in[9];
    float* out = (float*)d_out;

    char* ws = (char*)d_ws;
    size_t off = 0;
    auto carve = [&](size_t bytes) { void* p = ws + off; off += (bytes + 255) & ~(size_t)255; return p; };

    unsigned short* zb  = (unsigned short*)carve((size_t)MPAD * LATENT * 2);
    unsigned short* x1b = (unsigned short*)carve((size_t)MPAD * H1 * 2);
    unsigned short* x2b = (unsigned short*)carve((size_t)MPAD * HIDDEN * 2);
    unsigned short* W1t = (unsigned short*)carve((size_t)H1 * LATENT * 2);
    unsigned short* W2t = (unsigned short*)carve((size_t)HIDDEN * H1 * 2);
    unsigned short* Wgt = (unsigned short*)carve((size_t)(HEADS * OUT_D) * HIDDEN * 2);
    unsigned short* hb  = (unsigned short*)carve((size_t)MPAD * HEADS * OUT_D * 2);
    float* a_src = (float*)carve((size_t)N_NODES * HEADS * 4);
    float* a_dst = (float*)carve((size_t)N_NODES * HEADS * 4);
    int* deg       = (int*)carve((size_t)N_NODES * 4);
    int* tmp_scan  = (int*)carve((size_t)N_NODES * 4);
    int* bsum      = (int*)carve((size_t)NBLK_SCAN * 4);
    int* boff      = (int*)carve((size_t)NBLK_SCAN * 4);
    int* row_start = (int*)carve((size_t)N_NODES * 4);
    int* cursor    = (int*)carve((size_t)N_NODES * 4);
    int* adj       = (int*)carve((size_t)(E_EDGES + N_NODES) * 4);
    float* elog    = (float*)carve((size_t)(E_EDGES + N_NODES) * HEADS * 4);

    hipMemsetAsync(deg, 0, (size_t)N_NODES * 4, stream);

    // one merged conversion launch
    const int conv_total = SEG0 + SEG1 + SEG2 + SEG3;
    convert_all<<<(conv_total + 255) / 256, 256, 0, stream>>>(z, W1, W2, Wg, zb, W1t, W2t, Wgt);

    // CSR skeleton (independent of GEMMs)
    hist_kernel<<<(E_EDGES + 255) / 256, 256, 0, stream>>>(ei, deg);
    scan_a<<<NBLK_SCAN, 256, 0, stream>>>(deg, tmp_scan, bsum);
    scan_b<<<1, 64, 0, stream>>>(bsum, boff);
    scan_c<<<NBLK_SCAN, 256, 0, stream>>>(tmp_scan, deg, boff, row_start, cursor);

    // GEMMs (MFMA, 64x128 tiles -> 628..1256 blocks for latency hiding)
    gemm_mfma_bt<1><<<dim3(H1 / 128, MPAD / 64), 256, 0, stream>>>(zb,  W1t, b1, x1b, LATENT, H1, 1);
    gemm_mfma_bt<1><<<dim3(HIDDEN / 128, MPAD / 64), 256, 0, stream>>>(x1b, W2t, b2, x2b, H1, HIDDEN, 1);
    gemm_mfma_bt<1><<<dim3((HEADS * OUT_D) / 128, MPAD / 64), 256, 0, stream>>>(x2b, Wgt, nullptr, hb, HIDDEN, HEADS * OUT_D, 0);

    // attention coefficients (wave-per-node, vectorized)
    att_coef_kernel<<<(N_NODES + 3) / 4, 256, 0, stream>>>(hb, att_src, att_dst, a_src, a_dst);

    // edge scatter + logit precompute (edge-parallel latency hiding)
    scatter_logits<<<(E_EDGES + N_NODES + 255) / 256, 256, 0, stream>>>(
        ei, cursor, row_start, deg, a_src, a_dst, adj, elog);

    // fused softmax + aggregate (no atomics)
    fused_gat<<<N_NODES, 256, 0, stream>>>(adj, row_start, deg, elog, hb, bias_g, out);
}

// Round 6
// 218.936 us; speedup vs baseline: 1.1402x; 1.0224x over previous
//
#include <hip/hip_runtime.h>
#include <hip/hip_bf16.h>

#define N_NODES 20000
#define MPAD    20096   // 314 * 64
#define E_EDGES 400000
#define LATENT 128
#define H1 256
#define HIDDEN 512
#define OUT_D 64
#define HEADS 4
#define NEG_SLOPE 0.2f
#define NBLK_SCAN ((N_NODES + 255) / 256)   // 79

typedef __attribute__((ext_vector_type(8))) __bf16 bf16x8;
typedef __attribute__((ext_vector_type(4))) float f32x4;
typedef __attribute__((ext_vector_type(4))) unsigned short u16x4;

__device__ __forceinline__ unsigned short f2bf(float f) {
    union { float f; unsigned int u; } v; v.f = f;
    unsigned int r = v.u + 0x7fffu + ((v.u >> 16) & 1u);  // RNE
    return (unsigned short)(r >> 16);
}
__device__ __forceinline__ float bf2f(unsigned short u) {
    union { unsigned int u; float f; } v; v.u = ((unsigned int)u) << 16;
    return v.f;
}

__device__ __forceinline__ void gl_lds16(const unsigned short* g, unsigned short* l) {
    __builtin_amdgcn_global_load_lds(
        (const __attribute__((address_space(1))) unsigned int*)g,
        (__attribute__((address_space(3))) unsigned int*)l,
        16, 0, 0);
}

// ---------------- weight fp32 [K][N] -> bf16 [N][K] transpose-convert (one launch) ----------------
#define SEG1 (LATENT * H1)
#define SEG2 (H1 * HIDDEN)
#define SEG3 (HIDDEN * HEADS * OUT_D)
__global__ void convert_weights(const float* __restrict__ W1, const float* __restrict__ W2,
                                const float* __restrict__ Wg,
                                unsigned short* __restrict__ W1t, unsigned short* __restrict__ W2t,
                                unsigned short* __restrict__ Wgt) {
    int t = blockIdx.x * blockDim.x + threadIdx.x;
    if (t < SEG1) { int k = t >> 8, n = t & 255; W1t[n * LATENT + k] = f2bf(W1[t]); return; }
    t -= SEG1;
    if (t < SEG2) { int k = t >> 9, n = t & 511; W2t[n * H1 + k] = f2bf(W2[t]); return; }
    t -= SEG2;
    if (t < SEG3) { int k = t >> 8, n = t & 255; Wgt[n * HIDDEN + k] = f2bf(Wg[t]); }
}

// ---------------- fused MLP layers 1+2: x2b = relu(relu(z@W1+b1)@W2+b2) ----------------
// Block = 64 rows. Activations live in LDS; weights read as B-fragments directly from
// global (L2-resident, 0.5 MB total). Swapped-operand MFMA throughout.
#define ZP1 136   // zbf row pitch (elems): 16B-aligned, uniform bank spread
#define XP1 264   // x1s row pitch
__global__ __launch_bounds__(256)
void mlp12_kernel(const float* __restrict__ z,
                  const unsigned short* __restrict__ W1t,
                  const unsigned short* __restrict__ W2t,
                  const float* __restrict__ b1, const float* __restrict__ b2,
                  unsigned short* __restrict__ x2b) {
    __shared__ unsigned short zbf[64 * ZP1];   // 17.4 KB
    __shared__ unsigned short x1s[64 * XP1];   // 33.8 KB
    const int tid = threadIdx.x;
    const int wave = tid >> 6, lane = tid & 63;
    const int m0 = blockIdx.x * 64;
    const int fr = lane & 15, q = lane >> 4;

    // ---- stage z tile: fp32 global -> bf16 LDS (row-clamped; garbage rows never read) ----
    {
        const int r = tid >> 2, c0 = (tid & 3) * 32;
        const int zrow = min(m0 + r, N_NODES - 1);
        const float* zp = z + (size_t)zrow * LATENT + c0;
#pragma unroll
        for (int i = 0; i < 8; i++) {
            f32x4 v = *(const f32x4*)(zp + i * 4);
            u16x4 p = { f2bf(v[0]), f2bf(v[1]), f2bf(v[2]), f2bf(v[3]) };
            *(u16x4*)(zbf + r * ZP1 + c0 + i * 4) = p;
        }
    }
    __syncthreads();

    // ---- layer 1: x1 = relu(z @ W1 + b1), N=256, K=128; wave n-range 64 ----
    {
        const int nb = wave * 64;
        f32x4 acc[4][4] = {};
#pragma unroll
        for (int kt = 0; kt < 4; kt++) {
            bf16x8 af[4], bfr[4];
#pragma unroll
            for (int t = 0; t < 4; t++)
                af[t] = *(const bf16x8*)(zbf + (t * 16 + fr) * ZP1 + kt * 32 + q * 8);
#pragma unroll
            for (int t = 0; t < 4; t++)
                bfr[t] = *(const bf16x8*)(W1t + (size_t)(nb + t * 16 + fr) * LATENT + kt * 32 + q * 8);
#pragma unroll
            for (int mt = 0; mt < 4; mt++)
#pragma unroll
                for (int nt = 0; nt < 4; nt++)
                    acc[mt][nt] = __builtin_amdgcn_mfma_f32_16x16x32_bf16(
                        bfr[nt], af[mt], acc[mt][nt], 0, 0, 0);
        }
        // epilogue: lane holds m=fr, n = nb+nt*16+q*4+r
#pragma unroll
        for (int nt = 0; nt < 4; nt++) {
            const int n = nb + nt * 16 + q * 4;
            const f32x4 bv = *(const f32x4*)(b1 + n);
#pragma unroll
            for (int mt = 0; mt < 4; mt++) {
                u16x4 p;
#pragma unroll
                for (int r = 0; r < 4; r++) p[r] = f2bf(fmaxf(acc[mt][nt][r] + bv[r], 0.f));
                *(u16x4*)(x1s + (mt * 16 + fr) * XP1 + n) = p;
            }
        }
    }
    __syncthreads();

    // ---- layer 2: x2 = relu(x1 @ W2 + b2), N=512, K=256; wave n-range 128 ----
    {
        const int nb = wave * 128;
        f32x4 acc[4][8] = {};
#pragma unroll
        for (int kt = 0; kt < 8; kt++) {
            bf16x8 af[4], bfr[8];
#pragma unroll
            for (int t = 0; t < 4; t++)
                af[t] = *(const bf16x8*)(x1s + (t * 16 + fr) * XP1 + kt * 32 + q * 8);
#pragma unroll
            for (int t = 0; t < 8; t++)
                bfr[t] = *(const bf16x8*)(W2t + (size_t)(nb + t * 16 + fr) * H1 + kt * 32 + q * 8);
#pragma unroll
            for (int mt = 0; mt < 4; mt++)
#pragma unroll
                for (int nt = 0; nt < 8; nt++)
                    acc[mt][nt] = __builtin_amdgcn_mfma_f32_16x16x32_bf16(
                        bfr[nt], af[mt], acc[mt][nt], 0, 0, 0);
        }
#pragma unroll
        for (int nt = 0; nt < 8; nt++) {
            const int n = nb + nt * 16 + q * 4;
            const f32x4 bv = *(const f32x4*)(b2 + n);
#pragma unroll
            for (int mt = 0; mt < 4; mt++) {
                u16x4 p;
#pragma unroll
                for (int r = 0; r < 4; r++) p[r] = f2bf(fmaxf(acc[mt][nt][r] + bv[r], 0.f));
                *(u16x4*)(x2b + (size_t)(m0 + mt * 16 + fr) * HIDDEN + n) = p;
            }
        }
    }
}

// ---------------- layer 3 + attention coefficients: hb = x2 @ Wg; a_src/a_dst fused ----------------
// Block = 64 rows; wave w computes n-range w*64 = exactly head w -> att dot products fall out
// of the accumulator registers (no extra pass over hb).
__global__ __launch_bounds__(256)
void proj_att_kernel(const unsigned short* __restrict__ x2b,
                     const unsigned short* __restrict__ Wgt,
                     const float* __restrict__ att_src, const float* __restrict__ att_dst,
                     unsigned short* __restrict__ hb,
                     float* __restrict__ a_src, float* __restrict__ a_dst) {
    __shared__ unsigned short As[64 * 64];   // 8 KB, BK=64 staging
    const int tid = threadIdx.x;
    const int wave = tid >> 6, lane = tid & 63;
    const int m0 = blockIdx.x * 64;
    const int fr = lane & 15, q = lane >> 4;
    const int lr = lane >> 3, lc = lane & 7;
    const int head = wave;

    f32x4 acc[4][4] = {};
    for (int k0 = 0; k0 < HIDDEN; k0 += 64) {
        __syncthreads();
        {   // stage 64x64 slice of x2b: 16 rows per wave, 2 instrs
            const int rbase = wave * 16;
            gl_lds16(x2b + (size_t)(m0 + rbase + lr) * HIDDEN + k0 + lc * 8, As + rbase * 64);
            gl_lds16(x2b + (size_t)(m0 + rbase + 8 + lr) * HIDDEN + k0 + lc * 8, As + (rbase + 8) * 64);
        }
        __syncthreads();
#pragma unroll
        for (int kt = 0; kt < 2; kt++) {
            bf16x8 af[4], bfr[4];
#pragma unroll
            for (int t = 0; t < 4; t++)
                af[t] = *(const bf16x8*)(As + (t * 16 + fr) * 64 + kt * 32 + q * 8);
#pragma unroll
            for (int t = 0; t < 4; t++)
                bfr[t] = *(const bf16x8*)(Wgt + (size_t)(head * 64 + t * 16 + fr) * HIDDEN + k0 + kt * 32 + q * 8);
#pragma unroll
            for (int mt = 0; mt < 4; mt++)
#pragma unroll
                for (int nt = 0; nt < 4; nt++)
                    acc[mt][nt] = __builtin_amdgcn_mfma_f32_16x16x32_bf16(
                        bfr[nt], af[mt], acc[mt][nt], 0, 0, 0);
        }
    }

    // att vectors for this wave's (head, q) slice
    f32x4 asv[4], adv[4];
#pragma unroll
    for (int nt = 0; nt < 4; nt++) {
        asv[nt] = *(const f32x4*)(att_src + head * OUT_D + nt * 16 + q * 4);
        adv[nt] = *(const f32x4*)(att_dst + head * OUT_D + nt * 16 + q * 4);
    }

    // epilogue: store hb + reduce att dots per node row
#pragma unroll
    for (int mt = 0; mt < 4; mt++) {
        const int row = m0 + mt * 16 + fr;
        float vs = 0.f, vd = 0.f;
#pragma unroll
        for (int nt = 0; nt < 4; nt++) {
            u16x4 p;
#pragma unroll
            for (int r = 0; r < 4; r++) {
                float x = acc[mt][nt][r];
                p[r] = f2bf(x);
                vs += x * asv[nt][r];
                vd += x * adv[nt][r];
            }
            *(u16x4*)(hb + (size_t)row * (HEADS * OUT_D) + head * OUT_D + nt * 16 + q * 4) = p;
        }
        vs += __shfl_xor(vs, 16, 64); vs += __shfl_xor(vs, 32, 64);
        vd += __shfl_xor(vd, 16, 64); vd += __shfl_xor(vd, 32, 64);
        if (q == 0 && row < N_NODES) {
            a_src[row * HEADS + head] = vs;
            a_dst[row * HEADS + head] = vd;
        }
    }
}

// ---------------- CSR build ----------------
__global__ void hist_kernel(const int* __restrict__ ei, int* __restrict__ deg) {
    int t = blockIdx.x * blockDim.x + threadIdx.x;
    if (t < E_EDGES) atomicAdd(&deg[ei[E_EDGES + t]], 1);
}

__global__ __launch_bounds__(256) void scan_a(const int* __restrict__ deg,
                                              int* __restrict__ t, int* __restrict__ bsum) {
    int i = blockIdx.x * 256 + threadIdx.x;
    int lane = threadIdx.x & 63, wave = threadIdx.x >> 6;
    int v = (i < N_NODES) ? deg[i] + 1 : 0;
    int s = v;
#pragma unroll
    for (int off = 1; off < 64; off <<= 1) {
        int u = __shfl_up(s, off, 64);
        if (lane >= off) s += u;
    }
    __shared__ int wsum[4];
    if (lane == 63) wsum[wave] = s;
    __syncthreads();
    int woff = 0;
    for (int w = 0; w < wave; w++) woff += wsum[w];
    s += woff;
    if (i < N_NODES) t[i] = s;
    if (threadIdx.x == 255) bsum[blockIdx.x] = s;
}

// scan_b merged in: each block sums its bsum prefix (79 entries max) itself.
__global__ __launch_bounds__(256) void scan_c(const int* __restrict__ t, const int* __restrict__ deg,
                                              const int* __restrict__ bsum,
                                              int* __restrict__ row_start, int* __restrict__ cursor) {
    __shared__ int boff_s;
    if (threadIdx.x < 64) {
        int s = 0;
        for (int i = threadIdx.x; i < blockIdx.x; i += 64) s += bsum[i];
#pragma unroll
        for (int off = 32; off > 0; off >>= 1) s += __shfl_xor(s, off, 64);
        if (threadIdx.x == 0) boff_s = s;
    }
    __syncthreads();
    int i = blockIdx.x * 256 + threadIdx.x;
    if (i >= N_NODES) return;
    int incl = t[i] + boff_s;
    int start = incl - (deg[i] + 1);
    row_start[i] = start;
    cursor[i] = start;
}

// ---------------- scatter edges + precompute leaky-relu'd logits (all 4 heads) ----------------
__global__ void scatter_logits(const int* __restrict__ ei, int* __restrict__ cursor,
                               const int* __restrict__ row_start, const int* __restrict__ deg,
                               const float* __restrict__ a_src, const float* __restrict__ a_dst,
                               int* __restrict__ adj, float* __restrict__ elog) {
    int t = blockIdx.x * blockDim.x + threadIdx.x;
    if (t >= E_EDGES + N_NODES) return;
    int s, d, slot;
    if (t < E_EDGES) {
        s = ei[t]; d = ei[E_EDGES + t];
        slot = atomicAdd(&cursor[d], 1);
    } else {
        s = d = t - E_EDGES;
        slot = row_start[d] + deg[d];
    }
    adj[slot] = s;
    f32x4 as = *(const f32x4*)(a_src + s * HEADS);
    f32x4 ad = *(const f32x4*)(a_dst + d * HEADS);
    f32x4 o;
#pragma unroll
    for (int h = 0; h < HEADS; h++) {
        float v = as[h] + ad[h];
        o[h] = (v > 0.f) ? v : NEG_SLOPE * v;
    }
    *(f32x4*)(elog + (size_t)slot * HEADS) = o;
}

// ---------------- fused segment-softmax + gather-aggregate: ONE WAVE PER NODE ----------------
// lane = (head = l>>4, slot/dims = l&15). No block barriers; wave-private LDS stash.
__global__ __launch_bounds__(256) void fused_gat(const int* __restrict__ adj,
                                                 const int* __restrict__ row_start,
                                                 const int* __restrict__ deg,
                                                 const float* __restrict__ elog,
                                                 const unsigned short* __restrict__ hb,
                                                 const float* __restrict__ bias_g,
                                                 float* __restrict__ out) {
    const int wave = threadIdx.x >> 6, lane = threadIdx.x & 63;
    const int d = blockIdx.x * 4 + wave;      // N_NODES % 4 == 0
    const int base = row_start[d];
    const int cnt = deg[d] + 1;
    const int h = lane >> 4, j = lane & 15;

    __shared__ float lw[4][HEADS][32];   // logits -> weights
    __shared__ int   si[4][32];          // src ids

    // pass 1: max over segment (stash logits + src ids for slots < 32)
    float mx = -1e30f;
    for (int e = j; e < cnt; e += 16) {
        float v = elog[(size_t)(base + e) * HEADS + h];
        if (e < 32) {
            lw[wave][h][e] = v;
            if (h == 0) si[wave][e] = adj[base + e];
        }
        mx = fmaxf(mx, v);
    }
#pragma unroll
    for (int off = 1; off < 16; off <<= 1) mx = fmaxf(mx, __shfl_xor(mx, off, 64));

    // pass 2: sum of exp
    float sm = 0.f;
    for (int e = j; e < cnt; e += 16) {
        float v = (e < 32) ? lw[wave][h][e] : elog[(size_t)(base + e) * HEADS + h];
        sm += __expf(v - mx);
    }
#pragma unroll
    for (int off = 1; off < 16; off <<= 1) sm += __shfl_xor(sm, off, 64);
    const float inv = 1.f / (sm + 1e-16f);

    // pass 3: normalized weights back into the stash
    for (int e = j; e < cnt && e < 32; e += 16)
        lw[wave][h][e] = __expf(lw[wave][h][e] - mx) * inv;

    // phase 2: weighted gather; lane covers (head h, dims j*4..j*4+3)
    float a0 = 0.f, a1 = 0.f, a2 = 0.f, a3 = 0.f;
    const int lim = cnt < 32 ? cnt : 32;
    int e = 0;
    for (; e + 1 < lim; e += 2) {
        int s1 = si[wave][e],     s2 = si[wave][e + 1];
        float w1 = lw[wave][h][e], w2 = lw[wave][h][e + 1];
        u16x4 h1 = *(const u16x4*)(hb + (size_t)s1 * (HEADS * OUT_D) + h * OUT_D + j * 4);
        u16x4 h2 = *(const u16x4*)(hb + (size_t)s2 * (HEADS * OUT_D) + h * OUT_D + j * 4);
        a0 += w1 * bf2f(h1[0]) + w2 * bf2f(h2[0]);
        a1 += w1 * bf2f(h1[1]) + w2 * bf2f(h2[1]);
        a2 += w1 * bf2f(h1[2]) + w2 * bf2f(h2[2]);
        a3 += w1 * bf2f(h1[3]) + w2 * bf2f(h2[3]);
    }
    for (; e < lim; e++) {
        int s = si[wave][e];
        float w = lw[wave][h][e];
        u16x4 hx = *(const u16x4*)(hb + (size_t)s * (HEADS * OUT_D) + h * OUT_D + j * 4);
        a0 += w * bf2f(hx[0]); a1 += w * bf2f(hx[1]);
        a2 += w * bf2f(hx[2]); a3 += w * bf2f(hx[3]);
    }
    for (int e2 = 32; e2 < cnt; e2++) {   // rare (deg >= 32)
        int s = adj[base + e2];
        float w = __expf(elog[(size_t)(base + e2) * HEADS + h] - mx) * inv;
        u16x4 hx = *(const u16x4*)(hb + (size_t)s * (HEADS * OUT_D) + h * OUT_D + j * 4);
        a0 += w * bf2f(hx[0]); a1 += w * bf2f(hx[1]);
        a2 += w * bf2f(hx[2]); a3 += w * bf2f(hx[3]);
    }

    // head mean: combine lanes h=0..3 at same j via xor-16/32
    a0 += __shfl_xor(a0, 16, 64); a0 += __shfl_xor(a0, 32, 64);
    a1 += __shfl_xor(a1, 16, 64); a1 += __shfl_xor(a1, 32, 64);
    a2 += __shfl_xor(a2, 16, 64); a2 += __shfl_xor(a2, 32, 64);
    a3 += __shfl_xor(a3, 16, 64); a3 += __shfl_xor(a3, 32, 64);
    if (lane < 16) {
        f32x4 bg = *(const f32x4*)(bias_g + lane * 4);
        f32x4 r = { 0.25f * a0 + bg[0], 0.25f * a1 + bg[1],
                    0.25f * a2 + bg[2], 0.25f * a3 + bg[3] };
        *(f32x4*)(out + (size_t)d * OUT_D + lane * 4) = r;
    }
}

extern "C" void kernel_launch(void* const* d_in, const int* in_sizes, int n_in,
                              void* d_out, int out_size, void* d_ws, size_t ws_size,
                              hipStream_t stream) {
    const float* z       = (const float*)d_in[0];
    const float* W1      = (const float*)d_in[1];
    const float* b1      = (const float*)d_in[2];
    const float* W2      = (const float*)d_in[3];
    const float* b2      = (const float*)d_in[4];
    const float* Wg      = (const float*)d_in[5];
    const float* att_src = (const float*)d_in[6];
    const float* att_dst = (const float*)d_in[7];
    const float* bias_g  = (const float*)d_in[8];
    const int*   ei      = (const int*)d_in[9];
    float* out = (float*)d_out;

    char* ws = (char*)d_ws;
    size_t off = 0;
    auto carve = [&](size_t bytes) { void* p = ws + off; off += (bytes + 255) & ~(size_t)255; return p; };

    unsigned short* W1t = (unsigned short*)carve((size_t)H1 * LATENT * 2);
    unsigned short* W2t = (unsigned short*)carve((size_t)HIDDEN * H1 * 2);
    unsigned short* Wgt = (unsigned short*)carve((size_t)(HEADS * OUT_D) * HIDDEN * 2);
    unsigned short* x2b = (unsigned short*)carve((size_t)MPAD * HIDDEN * 2);
    unsigned short* hb  = (unsigned short*)carve((size_t)MPAD * HEADS * OUT_D * 2);
    float* a_src = (float*)carve((size_t)N_NODES * HEADS * 4);
    float* a_dst = (float*)carve((size_t)N_NODES * HEADS * 4);
    int* deg       = (int*)carve((size_t)N_NODES * 4);
    int* tmp_scan  = (int*)carve((size_t)N_NODES * 4);
    int* bsum      = (int*)carve((size_t)NBLK_SCAN * 4);
    int* row_start = (int*)carve((size_t)N_NODES * 4);
    int* cursor    = (int*)carve((size_t)N_NODES * 4);
    int* adj       = (int*)carve((size_t)(E_EDGES + N_NODES) * 4);
    float* elog    = (float*)carve((size_t)(E_EDGES + N_NODES) * HEADS * 4);

    hipMemsetAsync(deg, 0, (size_t)N_NODES * 4, stream);

    // weights -> bf16 transposed (one launch)
    const int wtot = SEG1 + SEG2 + SEG3;
    convert_weights<<<(wtot + 255) / 256, 256, 0, stream>>>(W1, W2, Wg, W1t, W2t, Wgt);

    // CSR skeleton
    hist_kernel<<<(E_EDGES + 255) / 256, 256, 0, stream>>>(ei, deg);
    scan_a<<<NBLK_SCAN, 256, 0, stream>>>(deg, tmp_scan, bsum);
    scan_c<<<NBLK_SCAN, 256, 0, stream>>>(tmp_scan, deg, bsum, row_start, cursor);

    // fused MLP (layers 1+2), then projection + attention coefficients
    mlp12_kernel<<<MPAD / 64, 256, 0, stream>>>(z, W1t, W2t, b1, b2, x2b);
    proj_att_kernel<<<MPAD / 64, 256, 0, stream>>>(x2b, Wgt, att_src, att_dst, hb, a_src, a_dst);

    // edge scatter + logits
    scatter_logits<<<(E_EDGES + N_NODES + 255) / 256, 256, 0, stream>>>(
        ei, cursor, row_start, deg, a_src, a_dst, adj, elog);

    // fused softmax + aggregate (wave-per-node, no barriers, no atomics)
    fused_gat<<<N_NODES / 4, 256, 0, stream>>>(adj, row_start, deg, elog, hb, bias_g, out);
}

// Round 7
// 218.158 us; speedup vs baseline: 1.1442x; 1.0036x over previous
//
#include <hip/hip_runtime.h>
#include <hip/hip_bf16.h>

#define N_NODES 20000
#define MPAD    20096
#define E_EDGES 400000
#define LATENT 128
#define H1 256
#define HIDDEN 512
#define OUT_D 64
#define HEADS 4
#define NEG_SLOPE 0.2f
#define NBLK_SCAN ((N_NODES + 255) / 256)   // 79

typedef __attribute__((ext_vector_type(8))) __bf16 bf16x8;
typedef __attribute__((ext_vector_type(4))) float f32x4;
typedef __attribute__((ext_vector_type(4))) unsigned short u16x4;

__device__ __forceinline__ unsigned short f2bf(float f) {
    union { float f; unsigned int u; } v; v.f = f;
    unsigned int r = v.u + 0x7fffu + ((v.u >> 16) & 1u);  // RNE
    return (unsigned short)(r >> 16);
}
__device__ __forceinline__ float bf2f(unsigned short u) {
    union { unsigned int u; float f; } v; v.u = ((unsigned int)u) << 16;
    return v.f;
}

// ---------------- weights transpose-convert + degree histogram (ONE launch) ----------------
#define SEG1 (LATENT * H1)
#define SEG2 (H1 * HIDDEN)
#define SEG3 (HIDDEN * HEADS * OUT_D)
#define WTOT (SEG1 + SEG2 + SEG3)
__global__ __launch_bounds__(256)
void prep_kernel(const float* __restrict__ W1, const float* __restrict__ W2,
                 const float* __restrict__ Wg, const int* __restrict__ ei,
                 unsigned short* __restrict__ W1t, unsigned short* __restrict__ W2t,
                 unsigned short* __restrict__ Wgt, int* __restrict__ deg) {
    int t = blockIdx.x * blockDim.x + threadIdx.x;
    if (t < SEG1) { int k = t >> 8, n = t & 255; W1t[n * LATENT + k] = f2bf(W1[t]); return; }
    t -= SEG1;
    if (t < SEG2) { int k = t >> 9, n = t & 511; W2t[n * H1 + k] = f2bf(W2[t]); return; }
    t -= SEG2;
    if (t < SEG3) { int k = t >> 8, n = t & 255; Wgt[n * HIDDEN + k] = f2bf(Wg[t]); return; }
    t -= SEG3;
    if (t < E_EDGES) atomicAdd(&deg[ei[E_EDGES + t]], 1);
}

// ---------------- fully fused MLP: hb = (relu(relu(z@W1+b1)@W2+b2)) @ Wg, + att coefs ----------------
// 32-row tiles -> 628 blocks. x1 and x2 live entirely in LDS (bank-padded pitches).
// Weights read as L2-resident global B-fragments. 3 barriers per block total.
#define TM 32
#define ZPITCH 136    // 128+8 elems: row stride 272 B -> +4 banks per row
#define XPITCH 264    // 256+8
#define X2PITCH 520   // 512+8
__global__ __launch_bounds__(256)
void mlp_all_kernel(const float* __restrict__ z,
                    const unsigned short* __restrict__ W1t,
                    const unsigned short* __restrict__ W2t,
                    const unsigned short* __restrict__ Wgt,
                    const float* __restrict__ b1, const float* __restrict__ b2,
                    const float* __restrict__ att_src, const float* __restrict__ att_dst,
                    unsigned short* __restrict__ hb,
                    float* __restrict__ a_src, float* __restrict__ a_dst) {
    __shared__ unsigned short zbf[TM * ZPITCH];    // 8.5 KB
    __shared__ unsigned short x1s[TM * XPITCH];    // 16.5 KB
    __shared__ unsigned short x2s[TM * X2PITCH];   // 32.5 KB  (57.5 KB total)
    const int tid = threadIdx.x;
    const int wave = tid >> 6, lane = tid & 63;
    const int m0 = blockIdx.x * TM;
    const int fr = lane & 15, q = lane >> 4;

    // ---- stage z tile: fp32 global -> bf16 LDS (rows clamped; garbage rows never used) ----
    {
        const int r = tid >> 3, c0 = (tid & 7) * 16;
        const int zrow = min(m0 + r, N_NODES - 1);
        const float* zp = z + (size_t)zrow * LATENT + c0;
#pragma unroll
        for (int i = 0; i < 4; i++) {
            f32x4 v = *(const f32x4*)(zp + i * 4);
            u16x4 p = { f2bf(v[0]), f2bf(v[1]), f2bf(v[2]), f2bf(v[3]) };
            *(u16x4*)(zbf + r * ZPITCH + c0 + i * 4) = p;
        }
    }
    __syncthreads();

    // ---- layer 1: x1 = relu(z @ W1 + b1), N=256, K=128; wave n-range 64 ----
    {
        const int nb = wave * 64;
        f32x4 acc[2][4] = {};
#pragma unroll
        for (int kt = 0; kt < 4; kt++) {
            bf16x8 af[2], bfr[4];
#pragma unroll
            for (int t = 0; t < 2; t++)
                af[t] = *(const bf16x8*)(zbf + (t * 16 + fr) * ZPITCH + kt * 32 + q * 8);
#pragma unroll
            for (int t = 0; t < 4; t++)
                bfr[t] = *(const bf16x8*)(W1t + (size_t)(nb + t * 16 + fr) * LATENT + kt * 32 + q * 8);
#pragma unroll
            for (int mt = 0; mt < 2; mt++)
#pragma unroll
                for (int nt = 0; nt < 4; nt++)
                    acc[mt][nt] = __builtin_amdgcn_mfma_f32_16x16x32_bf16(
                        bfr[nt], af[mt], acc[mt][nt], 0, 0, 0);
        }
#pragma unroll
        for (int nt = 0; nt < 4; nt++) {
            const int n = nb + nt * 16 + q * 4;
            const f32x4 bv = *(const f32x4*)(b1 + n);
#pragma unroll
            for (int mt = 0; mt < 2; mt++) {
                u16x4 p;
#pragma unroll
                for (int r = 0; r < 4; r++) p[r] = f2bf(fmaxf(acc[mt][nt][r] + bv[r], 0.f));
                *(u16x4*)(x1s + (mt * 16 + fr) * XPITCH + n) = p;
            }
        }
    }
    __syncthreads();

    // ---- layer 2: x2 = relu(x1 @ W2 + b2), N=512, K=256; wave n-range 128; out to LDS ----
    {
        const int nb = wave * 128;
        f32x4 acc[2][8] = {};
#pragma unroll
        for (int kt = 0; kt < 8; kt++) {
            bf16x8 af[2], bfr[8];
#pragma unroll
            for (int t = 0; t < 2; t++)
                af[t] = *(const bf16x8*)(x1s + (t * 16 + fr) * XPITCH + kt * 32 + q * 8);
#pragma unroll
            for (int t = 0; t < 8; t++)
                bfr[t] = *(const bf16x8*)(W2t + (size_t)(nb + t * 16 + fr) * H1 + kt * 32 + q * 8);
#pragma unroll
            for (int mt = 0; mt < 2; mt++)
#pragma unroll
                for (int nt = 0; nt < 8; nt++)
                    acc[mt][nt] = __builtin_amdgcn_mfma_f32_16x16x32_bf16(
                        bfr[nt], af[mt], acc[mt][nt], 0, 0, 0);
        }
#pragma unroll
        for (int nt = 0; nt < 8; nt++) {
            const int n = nb + nt * 16 + q * 4;
            const f32x4 bv = *(const f32x4*)(b2 + n);
#pragma unroll
            for (int mt = 0; mt < 2; mt++) {
                u16x4 p;
#pragma unroll
                for (int r = 0; r < 4; r++) p[r] = f2bf(fmaxf(acc[mt][nt][r] + bv[r], 0.f));
                *(u16x4*)(x2s + (mt * 16 + fr) * X2PITCH + n) = p;
            }
        }
    }
    __syncthreads();

    // ---- layer 3: h = x2 @ Wg, N=256 (wave = head, n-range 64), K=512; + att epilogue ----
    {
        const int head = wave;
        f32x4 acc[2][4] = {};
#pragma unroll
        for (int kt = 0; kt < 16; kt++) {
            bf16x8 af[2], bfr[4];
#pragma unroll
            for (int t = 0; t < 2; t++)
                af[t] = *(const bf16x8*)(x2s + (t * 16 + fr) * X2PITCH + kt * 32 + q * 8);
#pragma unroll
            for (int t = 0; t < 4; t++)
                bfr[t] = *(const bf16x8*)(Wgt + (size_t)(head * 64 + t * 16 + fr) * HIDDEN + kt * 32 + q * 8);
#pragma unroll
            for (int mt = 0; mt < 2; mt++)
#pragma unroll
                for (int nt = 0; nt < 4; nt++)
                    acc[mt][nt] = __builtin_amdgcn_mfma_f32_16x16x32_bf16(
                        bfr[nt], af[mt], acc[mt][nt], 0, 0, 0);
        }

        f32x4 asv[4], adv[4];
#pragma unroll
        for (int nt = 0; nt < 4; nt++) {
            asv[nt] = *(const f32x4*)(att_src + head * OUT_D + nt * 16 + q * 4);
            adv[nt] = *(const f32x4*)(att_dst + head * OUT_D + nt * 16 + q * 4);
        }
#pragma unroll
        for (int mt = 0; mt < 2; mt++) {
            const int row = m0 + mt * 16 + fr;
            float vs = 0.f, vd = 0.f;
#pragma unroll
            for (int nt = 0; nt < 4; nt++) {
                u16x4 p;
#pragma unroll
                for (int r = 0; r < 4; r++) {
                    float x = acc[mt][nt][r];
                    p[r] = f2bf(x);
                    vs += x * asv[nt][r];
                    vd += x * adv[nt][r];
                }
                *(u16x4*)(hb + (size_t)row * (HEADS * OUT_D) + head * OUT_D + nt * 16 + q * 4) = p;
            }
            vs += __shfl_xor(vs, 16, 64); vs += __shfl_xor(vs, 32, 64);
            vd += __shfl_xor(vd, 16, 64); vd += __shfl_xor(vd, 32, 64);
            if (q == 0 && row < N_NODES) {
                a_src[row * HEADS + head] = vs;
                a_dst[row * HEADS + head] = vd;
            }
        }
    }
}

// ---------------- CSR build ----------------
__global__ __launch_bounds__(256) void scan_a(const int* __restrict__ deg,
                                              int* __restrict__ t, int* __restrict__ bsum) {
    int i = blockIdx.x * 256 + threadIdx.x;
    int lane = threadIdx.x & 63, wave = threadIdx.x >> 6;
    int v = (i < N_NODES) ? deg[i] + 1 : 0;
    int s = v;
#pragma unroll
    for (int off = 1; off < 64; off <<= 1) {
        int u = __shfl_up(s, off, 64);
        if (lane >= off) s += u;
    }
    __shared__ int wsum[4];
    if (lane == 63) wsum[wave] = s;
    __syncthreads();
    int woff = 0;
    for (int w = 0; w < wave; w++) woff += wsum[w];
    s += woff;
    if (i < N_NODES) t[i] = s;
    if (threadIdx.x == 255) bsum[blockIdx.x] = s;
}

__global__ __launch_bounds__(256) void scan_c(const int* __restrict__ t, const int* __restrict__ deg,
                                              const int* __restrict__ bsum,
                                              int* __restrict__ row_start, int* __restrict__ cursor) {
    __shared__ int boff_s;
    if (threadIdx.x < 64) {
        int s = 0;
        for (int i = threadIdx.x; i < blockIdx.x; i += 64) s += bsum[i];
#pragma unroll
        for (int off = 32; off > 0; off >>= 1) s += __shfl_xor(s, off, 64);
        if (threadIdx.x == 0) boff_s = s;
    }
    __syncthreads();
    int i = blockIdx.x * 256 + threadIdx.x;
    if (i >= N_NODES) return;
    int incl = t[i] + boff_s;
    int start = incl - (deg[i] + 1);
    row_start[i] = start;
    cursor[i] = start;
}

// ---------------- scatter edges + precompute leaky-relu'd logits ----------------
__global__ void scatter_logits(const int* __restrict__ ei, int* __restrict__ cursor,
                               const int* __restrict__ row_start, const int* __restrict__ deg,
                               const float* __restrict__ a_src, const float* __restrict__ a_dst,
                               int* __restrict__ adj, float* __restrict__ elog) {
    int t = blockIdx.x * blockDim.x + threadIdx.x;
    if (t >= E_EDGES + N_NODES) return;
    int s, d, slot;
    if (t < E_EDGES) {
        s = ei[t]; d = ei[E_EDGES + t];
        slot = atomicAdd(&cursor[d], 1);
    } else {
        s = d = t - E_EDGES;
        slot = row_start[d] + deg[d];
    }
    adj[slot] = s;
    f32x4 as = *(const f32x4*)(a_src + s * HEADS);
    f32x4 ad = *(const f32x4*)(a_dst + d * HEADS);
    f32x4 o;
#pragma unroll
    for (int h = 0; h < HEADS; h++) {
        float v = as[h] + ad[h];
        o[h] = (v > 0.f) ? v : NEG_SLOPE * v;
    }
    *(f32x4*)(elog + (size_t)slot * HEADS) = o;
}

// ---------------- fused segment-softmax + gather-aggregate: one wave per node ----------------
__global__ __launch_bounds__(256) void fused_gat(const int* __restrict__ adj,
                                                 const int* __restrict__ row_start,
                                                 const int* __restrict__ deg,
                                                 const float* __restrict__ elog,
                                                 const unsigned short* __restrict__ hb,
                                                 const float* __restrict__ bias_g,
                                                 float* __restrict__ out) {
    const int wave = threadIdx.x >> 6, lane = threadIdx.x & 63;
    const int d = blockIdx.x * 4 + wave;      // N_NODES % 4 == 0
    const int base = row_start[d];
    const int cnt = deg[d] + 1;
    const int h = lane >> 4, j = lane & 15;

    __shared__ float lw[4][HEADS][32];
    __shared__ int   si[4][32];

    float mx = -1e30f;
    for (int e = j; e < cnt; e += 16) {
        float v = elog[(size_t)(base + e) * HEADS + h];
        if (e < 32) {
            lw[wave][h][e] = v;
            if (h == 0) si[wave][e] = adj[base + e];
        }
        mx = fmaxf(mx, v);
    }
#pragma unroll
    for (int off = 1; off < 16; off <<= 1) mx = fmaxf(mx, __shfl_xor(mx, off, 64));

    float sm = 0.f;
    for (int e = j; e < cnt; e += 16) {
        float v = (e < 32) ? lw[wave][h][e] : elog[(size_t)(base + e) * HEADS + h];
        sm += __expf(v - mx);
    }
#pragma unroll
    for (int off = 1; off < 16; off <<= 1) sm += __shfl_xor(sm, off, 64);
    const float inv = 1.f / (sm + 1e-16f);

    for (int e = j; e < cnt && e < 32; e += 16)
        lw[wave][h][e] = __expf(lw[wave][h][e] - mx) * inv;

    float a0 = 0.f, a1 = 0.f, a2 = 0.f, a3 = 0.f;
    const int lim = cnt < 32 ? cnt : 32;
    int e = 0;
    for (; e + 1 < lim; e += 2) {
        int s1 = si[wave][e],     s2 = si[wave][e + 1];
        float w1 = lw[wave][h][e], w2 = lw[wave][h][e + 1];
        u16x4 h1 = *(const u16x4*)(hb + (size_t)s1 * (HEADS * OUT_D) + h * OUT_D + j * 4);
        u16x4 h2 = *(const u16x4*)(hb + (size_t)s2 * (HEADS * OUT_D) + h * OUT_D + j * 4);
        a0 += w1 * bf2f(h1[0]) + w2 * bf2f(h2[0]);
        a1 += w1 * bf2f(h1[1]) + w2 * bf2f(h2[1]);
        a2 += w1 * bf2f(h1[2]) + w2 * bf2f(h2[2]);
        a3 += w1 * bf2f(h1[3]) + w2 * bf2f(h2[3]);
    }
    for (; e < lim; e++) {
        int s = si[wave][e];
        float w = lw[wave][h][e];
        u16x4 hx = *(const u16x4*)(hb + (size_t)s * (HEADS * OUT_D) + h * OUT_D + j * 4);
        a0 += w * bf2f(hx[0]); a1 += w * bf2f(hx[1]);
        a2 += w * bf2f(hx[2]); a3 += w * bf2f(hx[3]);
    }
    for (int e2 = 32; e2 < cnt; e2++) {
        int s = adj[base + e2];
        float w = __expf(elog[(size_t)(base + e2) * HEADS + h] - mx) * inv;
        u16x4 hx = *(const u16x4*)(hb + (size_t)s * (HEADS * OUT_D) + h * OUT_D + j * 4);
        a0 += w * bf2f(hx[0]); a1 += w * bf2f(hx[1]);
        a2 += w * bf2f(hx[2]); a3 += w * bf2f(hx[3]);
    }

    a0 += __shfl_xor(a0, 16, 64); a0 += __shfl_xor(a0, 32, 64);
    a1 += __shfl_xor(a1, 16, 64); a1 += __shfl_xor(a1, 32, 64);
    a2 += __shfl_xor(a2, 16, 64); a2 += __shfl_xor(a2, 32, 64);
    a3 += __shfl_xor(a3, 16, 64); a3 += __shfl_xor(a3, 32, 64);
    if (lane < 16) {
        f32x4 bg = *(const f32x4*)(bias_g + lane * 4);
        f32x4 r = { 0.25f * a0 + bg[0], 0.25f * a1 + bg[1],
                    0.25f * a2 + bg[2], 0.25f * a3 + bg[3] };
        *(f32x4*)(out + (size_t)d * OUT_D + lane * 4) = r;
    }
}

extern "C" void kernel_launch(void* const* d_in, const int* in_sizes, int n_in,
                              void* d_out, int out_size, void* d_ws, size_t ws_size,
                              hipStream_t stream) {
    const float* z       = (const float*)d_in[0];
    const float* W1      = (const float*)d_in[1];
    const float* b1      = (const float*)d_in[2];
    const float* W2      = (const float*)d_in[3];
    const float* b2      = (const float*)d_in[4];
    const float* Wg      = (const float*)d_in[5];
    const float* att_src = (const float*)d_in[6];
    const float* att_dst = (const float*)d_in[7];
    const float* bias_g  = (const float*)d_in[8];
    const int*   ei      = (const int*)d_in[9];
    float* out = (float*)d_out;

    char* ws = (char*)d_ws;
    size_t off = 0;
    auto carve = [&](size_t bytes) { void* p = ws + off; off += (bytes + 255) & ~(size_t)255; return p; };

    unsigned short* W1t = (unsigned short*)carve((size_t)H1 * LATENT * 2);
    unsigned short* W2t = (unsigned short*)carve((size_t)HIDDEN * H1 * 2);
    unsigned short* Wgt = (unsigned short*)carve((size_t)(HEADS * OUT_D) * HIDDEN * 2);
    unsigned short* hb  = (unsigned short*)carve((size_t)MPAD * HEADS * OUT_D * 2);
    float* a_src = (float*)carve((size_t)N_NODES * HEADS * 4);
    float* a_dst = (float*)carve((size_t)N_NODES * HEADS * 4);
    int* deg       = (int*)carve((size_t)N_NODES * 4);
    int* tmp_scan  = (int*)carve((size_t)N_NODES * 4);
    int* bsum      = (int*)carve((size_t)NBLK_SCAN * 4);
    int* row_start = (int*)carve((size_t)N_NODES * 4);
    int* cursor    = (int*)carve((size_t)N_NODES * 4);
    int* adj       = (int*)carve((size_t)(E_EDGES + N_NODES) * 4);
    float* elog    = (float*)carve((size_t)(E_EDGES + N_NODES) * HEADS * 4);

    hipMemsetAsync(deg, 0, (size_t)N_NODES * 4, stream);

    // weights->bf16 transpose + degree histogram, one launch
    prep_kernel<<<(WTOT + E_EDGES + 255) / 256, 256, 0, stream>>>(
        W1, W2, Wg, ei, W1t, W2t, Wgt, deg);

    // CSR skeleton
    scan_a<<<NBLK_SCAN, 256, 0, stream>>>(deg, tmp_scan, bsum);
    scan_c<<<NBLK_SCAN, 256, 0, stream>>>(tmp_scan, deg, bsum, row_start, cursor);

    // fully fused MLP (3 layers + att coefs), 628 blocks
    mlp_all_kernel<<<MPAD / TM, 256, 0, stream>>>(
        z, W1t, W2t, Wgt, b1, b2, att_src, att_dst, hb, a_src, a_dst);

    // edge scatter + logits
    scatter_logits<<<(E_EDGES + N_NODES + 255) / 256, 256, 0, stream>>>(
        ei, cursor, row_start, deg, a_src, a_dst, adj, elog);

    // fused softmax + aggregate
    fused_gat<<<N_NODES / 4, 256, 0, stream>>>(adj, row_start, deg, elog, hb, bias_g, out);
}

// Round 8
// 214.075 us; speedup vs baseline: 1.1661x; 1.0191x over previous
//
#include <hip/hip_runtime.h>
#include <hip/hip_bf16.h>

#define N_NODES 20000
#define MPAD    20096
#define E_EDGES 400000
#define LATENT 128
#define H1 256
#define HIDDEN 512
#define OUT_D 64
#define HEADS 4
#define NEG_SLOPE 0.2f
#define NBLK_SCAN ((N_NODES + 255) / 256)   // 79

typedef __attribute__((ext_vector_type(8))) __bf16 bf16x8;
typedef __attribute__((ext_vector_type(4))) float f32x4;
typedef __attribute__((ext_vector_type(4))) unsigned short u16x4;

__device__ __forceinline__ unsigned short f2bf(float f) {
    union { float f; unsigned int u; } v; v.f = f;
    unsigned int r = v.u + 0x7fffu + ((v.u >> 16) & 1u);  // RNE
    return (unsigned short)(r >> 16);
}
__device__ __forceinline__ float bf2f(unsigned short u) {
    union { unsigned int u; float f; } v; v.u = ((unsigned int)u) << 16;
    return v.f;
}

// ---------------- weights transpose-convert + degree histogram (ONE launch) ----------------
#define SEG1 (LATENT * H1)
#define SEG2 (H1 * HIDDEN)
#define SEG3 (HIDDEN * HEADS * OUT_D)
#define WTOT (SEG1 + SEG2 + SEG3)
__global__ __launch_bounds__(256)
void prep_kernel(const float* __restrict__ W1, const float* __restrict__ W2,
                 const float* __restrict__ Wg, const int* __restrict__ ei,
                 unsigned short* __restrict__ W1t, unsigned short* __restrict__ W2t,
                 unsigned short* __restrict__ Wgt, int* __restrict__ deg) {
    int t = blockIdx.x * blockDim.x + threadIdx.x;
    if (t < SEG1) { int k = t >> 8, n = t & 255; W1t[n * LATENT + k] = f2bf(W1[t]); return; }
    t -= SEG1;
    if (t < SEG2) { int k = t >> 9, n = t & 511; W2t[n * H1 + k] = f2bf(W2[t]); return; }
    t -= SEG2;
    if (t < SEG3) { int k = t >> 8, n = t & 255; Wgt[n * HIDDEN + k] = f2bf(Wg[t]); return; }
    t -= SEG3;
    if (t < E_EDGES) atomicAdd(&deg[ei[E_EDGES + t]], 1);
}

// ---------------- fully fused MLP + att coefs ----------------
// 32-row tiles -> 628 blocks. x1/x2 in LDS; zbf ALIASES x2s (z dead before x2 written)
// -> 49 KB LDS -> 3 blocks/CU. Weight B-fragments double-buffered in registers
// (prefetch distance 1) so the L2 load latency overlaps the MFMA burst.
#define TM 32
#define ZPITCH 136
#define XPITCH 264
#define X2PITCH 520
__global__ __launch_bounds__(256)
void mlp_all_kernel(const float* __restrict__ z,
                    const unsigned short* __restrict__ W1t,
                    const unsigned short* __restrict__ W2t,
                    const unsigned short* __restrict__ Wgt,
                    const float* __restrict__ b1, const float* __restrict__ b2,
                    const float* __restrict__ att_src, const float* __restrict__ att_dst,
                    unsigned short* __restrict__ hb,
                    float* __restrict__ a_src, float* __restrict__ a_dst) {
    __shared__ unsigned short x2s[TM * X2PITCH];   // 33.3 KB; first 8.5 KB aliased as zbf
    __shared__ unsigned short x1s[TM * XPITCH];    // 16.9 KB   (total 50.2 KB -> 3 blocks/CU)
    unsigned short* zbf = x2s;                     // alias: z tile dead before x2 written
    const int tid = threadIdx.x;
    const int wave = tid >> 6, lane = tid & 63;
    const int m0 = blockIdx.x * TM;
    const int fr = lane & 15, q = lane >> 4;

#define LDW1(kt, t) (*(const bf16x8*)(W1t + (size_t)(nb1 + (t) * 16 + fr) * LATENT + (kt) * 32 + q * 8))
#define LDW2(kt, t) (*(const bf16x8*)(W2t + (size_t)(nb2 + (t) * 16 + fr) * H1     + (kt) * 32 + q * 8))
#define LDW3(kt, t) (*(const bf16x8*)(Wgt + (size_t)(nb3 + (t) * 16 + fr) * HIDDEN + (kt) * 32 + q * 8))

    const int nb1 = wave * 64;
    const int nb2 = wave * 128;
    const int nb3 = wave * 64;   // head = wave

    // ---- prefetch layer-1 kt=0 weights BEFORE z staging (overlaps VALU + barrier) ----
    bf16x8 w1a[4], w1b[4];
#pragma unroll
    for (int t = 0; t < 4; t++) w1a[t] = LDW1(0, t);

    // ---- stage z tile: fp32 global -> bf16 LDS ----
    {
        const int r = tid >> 3, c0 = (tid & 7) * 16;
        const int zrow = min(m0 + r, N_NODES - 1);
        const float* zp = z + (size_t)zrow * LATENT + c0;
#pragma unroll
        for (int i = 0; i < 4; i++) {
            f32x4 v = *(const f32x4*)(zp + i * 4);
            u16x4 p = { f2bf(v[0]), f2bf(v[1]), f2bf(v[2]), f2bf(v[3]) };
            *(u16x4*)(zbf + r * ZPITCH + c0 + i * 4) = p;
        }
    }
    __syncthreads();

    // ---- layer 1: x1 = relu(z @ W1 + b1), K=128 (4 kt), wave n-range 64 ----
    f32x4 acc1[2][4] = {};
#pragma unroll
    for (int kt = 0; kt < 4; kt++) {
        bf16x8* wc = (kt & 1) ? w1b : w1a;
        bf16x8* wn = (kt & 1) ? w1a : w1b;
        if (kt < 3) {
#pragma unroll
            for (int t = 0; t < 4; t++) wn[t] = LDW1(kt + 1, t);
        }
        bf16x8 af[2];
#pragma unroll
        for (int t = 0; t < 2; t++)
            af[t] = *(const bf16x8*)(zbf + (t * 16 + fr) * ZPITCH + kt * 32 + q * 8);
#pragma unroll
        for (int mt = 0; mt < 2; mt++)
#pragma unroll
            for (int nt = 0; nt < 4; nt++)
                acc1[mt][nt] = __builtin_amdgcn_mfma_f32_16x16x32_bf16(
                    wc[nt], af[mt], acc1[mt][nt], 0, 0, 0);
    }

    // prefetch layer-2 kt=0 weights (independent of x1s barrier)
    bf16x8 w2a[8], w2b[8];
#pragma unroll
    for (int t = 0; t < 8; t++) w2a[t] = LDW2(0, t);

    // layer-1 epilogue -> x1s
#pragma unroll
    for (int nt = 0; nt < 4; nt++) {
        const int n = nb1 + nt * 16 + q * 4;
        const f32x4 bv = *(const f32x4*)(b1 + n);
#pragma unroll
        for (int mt = 0; mt < 2; mt++) {
            u16x4 p;
#pragma unroll
            for (int r = 0; r < 4; r++) p[r] = f2bf(fmaxf(acc1[mt][nt][r] + bv[r], 0.f));
            *(u16x4*)(x1s + (mt * 16 + fr) * XPITCH + n) = p;
        }
    }
    __syncthreads();

    // ---- layer 2: x2 = relu(x1 @ W2 + b2), K=256 (8 kt), wave n-range 128 -> LDS ----
    f32x4 acc2[2][8] = {};
#pragma unroll
    for (int kt = 0; kt < 8; kt++) {
        bf16x8* wc = (kt & 1) ? w2b : w2a;
        bf16x8* wn = (kt & 1) ? w2a : w2b;
        if (kt < 7) {
#pragma unroll
            for (int t = 0; t < 8; t++) wn[t] = LDW2(kt + 1, t);
        }
        bf16x8 af[2];
#pragma unroll
        for (int t = 0; t < 2; t++)
            af[t] = *(const bf16x8*)(x1s + (t * 16 + fr) * XPITCH + kt * 32 + q * 8);
#pragma unroll
        for (int mt = 0; mt < 2; mt++)
#pragma unroll
            for (int nt = 0; nt < 8; nt++)
                acc2[mt][nt] = __builtin_amdgcn_mfma_f32_16x16x32_bf16(
                    wc[nt], af[mt], acc2[mt][nt], 0, 0, 0);
    }

    // prefetch layer-3 kt=0 weights
    bf16x8 w3a[4], w3b[4];
#pragma unroll
    for (int t = 0; t < 4; t++) w3a[t] = LDW3(0, t);

    __syncthreads();   // all layer-1 zbf reads done block-wide; x2s writes may clobber alias
#pragma unroll
    for (int nt = 0; nt < 8; nt++) {
        const int n = nb2 + nt * 16 + q * 4;
        const f32x4 bv = *(const f32x4*)(b2 + n);
#pragma unroll
        for (int mt = 0; mt < 2; mt++) {
            u16x4 p;
#pragma unroll
            for (int r = 0; r < 4; r++) p[r] = f2bf(fmaxf(acc2[mt][nt][r] + bv[r], 0.f));
            *(u16x4*)(x2s + (mt * 16 + fr) * X2PITCH + n) = p;
        }
    }
    __syncthreads();

    // ---- layer 3: h = x2 @ Wg, K=512 (16 kt), wave = head (n-range 64) + att epilogue ----
    f32x4 acc3[2][4] = {};
#pragma unroll
    for (int kt = 0; kt < 16; kt++) {
        bf16x8* wc = (kt & 1) ? w3b : w3a;
        bf16x8* wn = (kt & 1) ? w3a : w3b;
        if (kt < 15) {
#pragma unroll
            for (int t = 0; t < 4; t++) wn[t] = LDW3(kt + 1, t);
        }
        bf16x8 af[2];
#pragma unroll
        for (int t = 0; t < 2; t++)
            af[t] = *(const bf16x8*)(x2s + (t * 16 + fr) * X2PITCH + kt * 32 + q * 8);
#pragma unroll
        for (int mt = 0; mt < 2; mt++)
#pragma unroll
            for (int nt = 0; nt < 4; nt++)
                acc3[mt][nt] = __builtin_amdgcn_mfma_f32_16x16x32_bf16(
                    wc[nt], af[mt], acc3[mt][nt], 0, 0, 0);
    }

    {
        const int head = wave;
        f32x4 asv[4], adv[4];
#pragma unroll
        for (int nt = 0; nt < 4; nt++) {
            asv[nt] = *(const f32x4*)(att_src + head * OUT_D + nt * 16 + q * 4);
            adv[nt] = *(const f32x4*)(att_dst + head * OUT_D + nt * 16 + q * 4);
        }
#pragma unroll
        for (int mt = 0; mt < 2; mt++) {
            const int row = m0 + mt * 16 + fr;
            float vs = 0.f, vd = 0.f;
#pragma unroll
            for (int nt = 0; nt < 4; nt++) {
                u16x4 p;
#pragma unroll
                for (int r = 0; r < 4; r++) {
                    float x = acc3[mt][nt][r];
                    p[r] = f2bf(x);
                    vs += x * asv[nt][r];
                    vd += x * adv[nt][r];
                }
                *(u16x4*)(hb + (size_t)row * (HEADS * OUT_D) + head * OUT_D + nt * 16 + q * 4) = p;
            }
            vs += __shfl_xor(vs, 16, 64); vs += __shfl_xor(vs, 32, 64);
            vd += __shfl_xor(vd, 16, 64); vd += __shfl_xor(vd, 32, 64);
            if (q == 0 && row < N_NODES) {
                a_src[row * HEADS + head] = vs;
                a_dst[row * HEADS + head] = vd;
            }
        }
    }
#undef LDW1
#undef LDW2
#undef LDW3
}

// ---------------- CSR build ----------------
__global__ __launch_bounds__(256) void scan_a(const int* __restrict__ deg,
                                              int* __restrict__ t, int* __restrict__ bsum) {
    int i = blockIdx.x * 256 + threadIdx.x;
    int lane = threadIdx.x & 63, wave = threadIdx.x >> 6;
    int v = (i < N_NODES) ? deg[i] + 1 : 0;
    int s = v;
#pragma unroll
    for (int off = 1; off < 64; off <<= 1) {
        int u = __shfl_up(s, off, 64);
        if (lane >= off) s += u;
    }
    __shared__ int wsum[4];
    if (lane == 63) wsum[wave] = s;
    __syncthreads();
    int woff = 0;
    for (int w = 0; w < wave; w++) woff += wsum[w];
    s += woff;
    if (i < N_NODES) t[i] = s;
    if (threadIdx.x == 255) bsum[blockIdx.x] = s;
}

__global__ __launch_bounds__(256) void scan_c(const int* __restrict__ t, const int* __restrict__ deg,
                                              const int* __restrict__ bsum,
                                              int* __restrict__ row_start, int* __restrict__ cursor) {
    __shared__ int boff_s;
    if (threadIdx.x < 64) {
        int s = 0;
        for (int i = threadIdx.x; i < blockIdx.x; i += 64) s += bsum[i];
#pragma unroll
        for (int off = 32; off > 0; off >>= 1) s += __shfl_xor(s, off, 64);
        if (threadIdx.x == 0) boff_s = s;
    }
    __syncthreads();
    int i = blockIdx.x * 256 + threadIdx.x;
    if (i >= N_NODES) return;
    int incl = t[i] + boff_s;
    int start = incl - (deg[i] + 1);
    row_start[i] = start;
    cursor[i] = start;
}

// ---------------- scatter edges + precompute leaky-relu'd logits ----------------
__global__ void scatter_logits(const int* __restrict__ ei, int* __restrict__ cursor,
                               const int* __restrict__ row_start, const int* __restrict__ deg,
                               const float* __restrict__ a_src, const float* __restrict__ a_dst,
                               int* __restrict__ adj, float* __restrict__ elog) {
    int t = blockIdx.x * blockDim.x + threadIdx.x;
    if (t >= E_EDGES + N_NODES) return;
    int s, d, slot;
    if (t < E_EDGES) {
        s = ei[t]; d = ei[E_EDGES + t];
        slot = atomicAdd(&cursor[d], 1);
    } else {
        s = d = t - E_EDGES;
        slot = row_start[d] + deg[d];
    }
    adj[slot] = s;
    f32x4 as = *(const f32x4*)(a_src + s * HEADS);
    f32x4 ad = *(const f32x4*)(a_dst + d * HEADS);
    f32x4 o;
#pragma unroll
    for (int h = 0; h < HEADS; h++) {
        float v = as[h] + ad[h];
        o[h] = (v > 0.f) ? v : NEG_SLOPE * v;
    }
    *(f32x4*)(elog + (size_t)slot * HEADS) = o;
}

// ---------------- fused segment-softmax + gather-aggregate: one wave per node ----------------
__global__ __launch_bounds__(256) void fused_gat(const int* __restrict__ adj,
                                                 const int* __restrict__ row_start,
                                                 const int* __restrict__ deg,
                                                 const float* __restrict__ elog,
                                                 const unsigned short* __restrict__ hb,
                                                 const float* __restrict__ bias_g,
                                                 float* __restrict__ out) {
    const int wave = threadIdx.x >> 6, lane = threadIdx.x & 63;
    const int d = blockIdx.x * 4 + wave;      // N_NODES % 4 == 0
    const int base = row_start[d];
    const int cnt = deg[d] + 1;
    const int h = lane >> 4, j = lane & 15;

    __shared__ float lw[4][HEADS][32];
    __shared__ int   si[4][32];

    float mx = -1e30f;
    for (int e = j; e < cnt; e += 16) {
        float v = elog[(size_t)(base + e) * HEADS + h];
        if (e < 32) {
            lw[wave][h][e] = v;
            if (h == 0) si[wave][e] = adj[base + e];
        }
        mx = fmaxf(mx, v);
    }
#pragma unroll
    for (int off = 1; off < 16; off <<= 1) mx = fmaxf(mx, __shfl_xor(mx, off, 64));

    float sm = 0.f;
    for (int e = j; e < cnt; e += 16) {
        float v = (e < 32) ? lw[wave][h][e] : elog[(size_t)(base + e) * HEADS + h];
        sm += __expf(v - mx);
    }
#pragma unroll
    for (int off = 1; off < 16; off <<= 1) sm += __shfl_xor(sm, off, 64);
    const float inv = 1.f / (sm + 1e-16f);

    for (int e = j; e < cnt && e < 32; e += 16)
        lw[wave][h][e] = __expf(lw[wave][h][e] - mx) * inv;

    // phase 2: weighted gather, unroll-4 for 4 loads in flight
    float a0 = 0.f, a1 = 0.f, a2 = 0.f, a3 = 0.f;
    const int lim = cnt < 32 ? cnt : 32;
    const unsigned short* hp = hb + h * OUT_D + j * 4;
    int e = 0;
    for (; e + 3 < lim; e += 4) {
        int s0 = si[wave][e], s1 = si[wave][e + 1], s2 = si[wave][e + 2], s3 = si[wave][e + 3];
        float w0 = lw[wave][h][e],     w1 = lw[wave][h][e + 1];
        float w2 = lw[wave][h][e + 2], w3 = lw[wave][h][e + 3];
        u16x4 g0 = *(const u16x4*)(hp + (size_t)s0 * (HEADS * OUT_D));
        u16x4 g1 = *(const u16x4*)(hp + (size_t)s1 * (HEADS * OUT_D));
        u16x4 g2 = *(const u16x4*)(hp + (size_t)s2 * (HEADS * OUT_D));
        u16x4 g3 = *(const u16x4*)(hp + (size_t)s3 * (HEADS * OUT_D));
        a0 += w0 * bf2f(g0[0]) + w1 * bf2f(g1[0]) + w2 * bf2f(g2[0]) + w3 * bf2f(g3[0]);
        a1 += w0 * bf2f(g0[1]) + w1 * bf2f(g1[1]) + w2 * bf2f(g2[1]) + w3 * bf2f(g3[1]);
        a2 += w0 * bf2f(g0[2]) + w1 * bf2f(g1[2]) + w2 * bf2f(g2[2]) + w3 * bf2f(g3[2]);
        a3 += w0 * bf2f(g0[3]) + w1 * bf2f(g1[3]) + w2 * bf2f(g2[3]) + w3 * bf2f(g3[3]);
    }
    for (; e < lim; e++) {
        int s = si[wave][e];
        float w = lw[wave][h][e];
        u16x4 g = *(const u16x4*)(hp + (size_t)s * (HEADS * OUT_D));
        a0 += w * bf2f(g[0]); a1 += w * bf2f(g[1]);
        a2 += w * bf2f(g[2]); a3 += w * bf2f(g[3]);
    }
    for (int e2 = 32; e2 < cnt; e2++) {   // rare (deg >= 32)
        int s = adj[base + e2];
        float w = __expf(elog[(size_t)(base + e2) * HEADS + h] - mx) * inv;
        u16x4 g = *(const u16x4*)(hp + (size_t)s * (HEADS * OUT_D));
        a0 += w * bf2f(g[0]); a1 += w * bf2f(g[1]);
        a2 += w * bf2f(g[2]); a3 += w * bf2f(g[3]);
    }

    a0 += __shfl_xor(a0, 16, 64); a0 += __shfl_xor(a0, 32, 64);
    a1 += __shfl_xor(a1, 16, 64); a1 += __shfl_xor(a1, 32, 64);
    a2 += __shfl_xor(a2, 16, 64); a2 += __shfl_xor(a2, 32, 64);
    a3 += __shfl_xor(a3, 16, 64); a3 += __shfl_xor(a3, 32, 64);
    if (lane < 16) {
        f32x4 bg = *(const f32x4*)(bias_g + lane * 4);
        f32x4 r = { 0.25f * a0 + bg[0], 0.25f * a1 + bg[1],
                    0.25f * a2 + bg[2], 0.25f * a3 + bg[3] };
        *(f32x4*)(out + (size_t)d * OUT_D + lane * 4) = r;
    }
}

extern "C" void kernel_launch(void* const* d_in, const int* in_sizes, int n_in,
                              void* d_out, int out_size, void* d_ws, size_t ws_size,
                              hipStream_t stream) {
    const float* z       = (const float*)d_in[0];
    const float* W1      = (const float*)d_in[1];
    const float* b1      = (const float*)d_in[2];
    const float* W2      = (const float*)d_in[3];
    const float* b2      = (const float*)d_in[4];
    const float* Wg      = (const float*)d_in[5];
    const float* att_src = (const float*)d_in[6];
    const float* att_dst = (const float*)d_in[7];
    const float* bias_g  = (const float*)d_in[8];
    const int*   ei      = (const int*)d_in[9];
    float* out = (float*)d_out;

    char* ws = (char*)d_ws;
    size_t off = 0;
    auto carve = [&](size_t bytes) { void* p = ws + off; off += (bytes + 255) & ~(size_t)255; return p; };

    unsigned short* W1t = (unsigned short*)carve((size_t)H1 * LATENT * 2);
    unsigned short* W2t = (unsigned short*)carve((size_t)HIDDEN * H1 * 2);
    unsigned short* Wgt = (unsigned short*)carve((size_t)(HEADS * OUT_D) * HIDDEN * 2);
    unsigned short* hb  = (unsigned short*)carve((size_t)MPAD * HEADS * OUT_D * 2);
    float* a_src = (float*)carve((size_t)N_NODES * HEADS * 4);
    float* a_dst = (float*)carve((size_t)N_NODES * HEADS * 4);
    int* deg       = (int*)carve((size_t)N_NODES * 4);
    int* tmp_scan  = (int*)carve((size_t)N_NODES * 4);
    int* bsum      = (int*)carve((size_t)NBLK_SCAN * 4);
    int* row_start = (int*)carve((size_t)N_NODES * 4);
    int* cursor    = (int*)carve((size_t)N_NODES * 4);
    int* adj       = (int*)carve((size_t)(E_EDGES + N_NODES) * 4);
    float* elog    = (float*)carve((size_t)(E_EDGES + N_NODES) * HEADS * 4);

    hipMemsetAsync(deg, 0, (size_t)N_NODES * 4, stream);

    // weights->bf16 transpose + degree histogram, one launch
    prep_kernel<<<(WTOT + E_EDGES + 255) / 256, 256, 0, stream>>>(
        W1, W2, Wg, ei, W1t, W2t, Wgt, deg);

    // CSR skeleton
    scan_a<<<NBLK_SCAN, 256, 0, stream>>>(deg, tmp_scan, bsum);
    scan_c<<<NBLK_SCAN, 256, 0, stream>>>(tmp_scan, deg, bsum, row_start, cursor);

    // fully fused MLP (3 layers + att coefs), 628 blocks, 3 blocks/CU
    mlp_all_kernel<<<MPAD / TM, 256, 0, stream>>>(
        z, W1t, W2t, Wgt, b1, b2, att_src, att_dst, hb, a_src, a_dst);

    // edge scatter + logits
    scatter_logits<<<(E_EDGES + N_NODES + 255) / 256, 256, 0, stream>>>(
        ei, cursor, row_start, deg, a_src, a_dst, adj, elog);

    // fused softmax + aggregate
    fused_gat<<<N_NODES / 4, 256, 0, stream>>>(adj, row_start, deg, elog, hb, bias_g, out);
}